// Round 11
// baseline (159.096 us; speedup 1.0000x reference)
//
#include <hip/hip_runtime.h>

#define INF_BITS 0x7F800000u
#define AS1 __attribute__((address_space(1)))
#define AS3 __attribute__((address_space(3)))

typedef float f32x4 __attribute__((ext_vector_type(4)));
typedef __bf16 bf16x8 __attribute__((ext_vector_type(8)));
typedef unsigned short u16x4 __attribute__((ext_vector_type(4)));
typedef unsigned short u16x8 __attribute__((ext_vector_type(8)));
typedef unsigned int u32x4 __attribute__((ext_vector_type(4)));

static __device__ __forceinline__ unsigned short f2bf(float f) {
  unsigned int u = __float_as_uint(f);
  return (unsigned short)((u + 0x7FFFu + ((u >> 16) & 1u)) >> 16);  // RTNE
}

// ---- protos (2000x2048 f32) -> pT (2048x2048 bf16, pad rows zero) + p2 ----
// also initializes out's min-distance region to +inf (blocks 0..249)
__global__ __launch_bounds__(256) void k_prep_p(const float* __restrict__ protos,
                                                unsigned short* __restrict__ pT,
                                                float* __restrict__ p2,
                                                unsigned int* __restrict__ outu) {
  const int row = blockIdx.x;   // 2048
  const int tid = threadIdx.x;  // 256
  const int gi = row * 256 + tid;
  if (gi < 64000) outu[6400 + gi] = INF_BITS;
  __shared__ float red[4];
  float s = 0.f;
  u16x8 h = (u16x8){0, 0, 0, 0, 0, 0, 0, 0};
  if (row < 2000) {
    const float* src = protos + (size_t)row * 2048 + tid * 8;
    f32x4 a = *(const f32x4*)src;
    f32x4 c = *(const f32x4*)(src + 4);
    h = (u16x8){f2bf(a.x), f2bf(a.y), f2bf(a.z), f2bf(a.w),
                f2bf(c.x), f2bf(c.y), f2bf(c.z), f2bf(c.w)};
    s = a.x * a.x + a.y * a.y + a.z * a.z + a.w * a.w +
        c.x * c.x + c.y * c.y + c.z * c.z + c.w * c.w;
  }
  *(u16x8*)(pT + (size_t)row * 2048 + tid * 8) = h;
  #pragma unroll
  for (int off = 32; off; off >>= 1) s += __shfl_xor(s, off);
  if ((tid & 63) == 0) red[tid >> 6] = s;
  __syncthreads();
  if (tid == 0) p2[row] = red[0] + red[1] + red[2] + red[3];
}

// ---- x (b,k,n) f32 -> xT[(b*196+n)*2048+k] bf16 + x2 partials ----
__global__ __launch_bounds__(256) void k_prep_x(const float* __restrict__ x,
                                                unsigned short* __restrict__ xT,
                                                float* __restrict__ x2p,
                                                float* __restrict__ x2) {
  const int kt = blockIdx.x;  // 32
  const int b  = blockIdx.y;  // 33: b==32 -> padding work
  const int tid = threadIdx.x;
  if (b == 32) {
    u32x4* pad = (u32x4*)(xT + (size_t)6272 * 2048);
    #pragma unroll
    for (int j = tid; j < 1024; j += 256)
      pad[kt * 1024 + j] = (u32x4){0u, 0u, 0u, 0u};
    if (kt == 0 && tid < 128) x2[6272 + tid] = __uint_as_float(INF_BITS);
    return;
  }
  __shared__ unsigned short Ls[64][204];  // stride 204: 8B-aligned u16x4 stores
  const float* src = x + ((size_t)b * 2048 + (size_t)kt * 64) * 196;
  for (int idx = tid; idx < 3136; idx += 256) {
    const int kk = idx / 49, c4 = idx - kk * 49;
    f32x4 v = *(const f32x4*)(src + (size_t)kk * 196 + c4 * 4);
    *(u16x4*)&Ls[kk][c4 * 4] = (u16x4){f2bf(v.x), f2bf(v.y), f2bf(v.z), f2bf(v.w)};
  }
  __syncthreads();
  if (tid < 196) {
    float s = 0.f;
    #pragma unroll
    for (int j = 0; j < 64; ++j) {
      float v = __uint_as_float((unsigned int)Ls[j][tid] << 16);
      s += v * v;
    }
    x2p[kt * 6272 + b * 196 + tid] = s;
  }
  unsigned short* dstb = xT + (size_t)b * 196 * 2048 + kt * 64;
  for (int idx = tid; idx < 1568; idx += 256) {
    const int n = idx >> 3, q = idx & 7;
    const int k0 = q * 8;
    u32x4 v;
    v.x = (unsigned int)Ls[k0 + 0][n] | ((unsigned int)Ls[k0 + 1][n] << 16);
    v.y = (unsigned int)Ls[k0 + 2][n] | ((unsigned int)Ls[k0 + 3][n] << 16);
    v.z = (unsigned int)Ls[k0 + 4][n] | ((unsigned int)Ls[k0 + 5][n] << 16);
    v.w = (unsigned int)Ls[k0 + 6][n] | ((unsigned int)Ls[k0 + 7][n] << 16);
    *(u32x4*)(dstb + (size_t)n * 2048 + k0) = v;
  }
}

__global__ void k_x2r(const float* __restrict__ x2p, float* __restrict__ x2) {
  int i = blockIdx.x * blockDim.x + threadIdx.x;
  if (i >= 6272) return;
  float s = 0.f;
  #pragma unroll
  for (int c = 0; c < 32; ++c) s += x2p[c * 6272 + i];
  x2[i] = s;
}

// ---- main GEMM: 256x256 tile, BK=64, 8 waves; cross-half-tile read-ahead:
// READ kh0 | MFMA(prev kh1) | READ kh1 | MFMA(kh0) -> LDS service overlaps MFMA
__global__ __launch_bounds__(512, 2) void k_main(
    const unsigned short* __restrict__ pT, const unsigned short* __restrict__ xT,
    const float* __restrict__ p2, const float* __restrict__ x2,
    unsigned int* __restrict__ outu) {
  const int orig = blockIdx.x;
  const int wgid = (orig & 7) * 25 + (orig >> 3);
  const int ptpair = wgid / 50;
  const int rem = wgid - ptpair * 50;
  const int ptile = ptpair * 2 + (rem & 1);  // 0..7
  const int mtile = rem >> 1;                // 0..24
  const int p0 = ptile * 256;
  const int m0 = mtile * 256;
  const int tid = threadIdx.x;
  const int lane = tid & 63;
  const int w = tid >> 6;   // 8 waves
  const int wp = w >> 2;    // A half (128 rows)
  const int wn = w & 3;     // B quarter (64 rows)
  const int lr = lane & 15;
  const int lg = lane >> 4;

  __shared__ __align__(16) char S[131072];  // A[2]:0..64K, B[2]:64K..128K

  f32x4 acc[8][4];
  #pragma unroll
  for (int mi = 0; mi < 8; ++mi)
    #pragma unroll
    for (int ni = 0; ni < 4; ++ni)
      acc[mi][ni] = (f32x4){0.f, 0.f, 0.f, 0.f};

  const int rowbase = tid >> 3;                       // 0..63
  const int chunk = (tid & 7) ^ (rowbase & 7);        // involution
  const char* gA = (const char*)pT + (size_t)(p0 + rowbase) * 4096 + chunk * 16;
  const char* gB = (const char*)xT + (size_t)(m0 + rowbase) * 4096 + chunk * 16;
  const int wbase = w * 1024;

#define STAGE_A(c_, kt_, h_) do {                                              \
    const char* s_ = gA + (size_t)((h_) * 128 * 4096) + (size_t)(kt_) * 128;   \
    _Pragma("unroll")                                                          \
    for (int j_ = 0; j_ < 2; ++j_)                                             \
      __builtin_amdgcn_global_load_lds(                                        \
          (const AS1 void*)(s_ + (size_t)j_ * 64 * 4096),                      \
          (AS3 void*)(S + (c_) * 32768 + (h_) * 16384 + j_ * 8192 + wbase),    \
          16, 0, 0);                                                           \
  } while (0)
#define STAGE_B(c_, kt_, h_) do {                                              \
    const char* s_ = gB + (size_t)((h_) * 128 * 4096) + (size_t)(kt_) * 128;   \
    _Pragma("unroll")                                                          \
    for (int j_ = 0; j_ < 2; ++j_)                                             \
      __builtin_amdgcn_global_load_lds(                                        \
          (const AS1 void*)(s_ + (size_t)j_ * 64 * 4096),                      \
          (AS3 void*)(S + 65536 + (c_) * 32768 + (h_) * 16384 + j_ * 8192 + wbase), \
          16, 0, 0);                                                           \
  } while (0)
#define STAGE_FULL(c_, kt_) do {                                               \
    STAGE_A(c_, kt_, 0); STAGE_A(c_, kt_, 1);                                  \
    STAGE_B(c_, kt_, 0); STAGE_B(c_, kt_, 1); } while (0)

  const int swz = ((lr & 7) << 4);
  const int arow = (wp * 128 + lr) * 128;        // + (mi>>2)*8192 + (mi&3)*2048
  const int brow = (wn * 64 + lr) * 128;         // + ni*2048 (B region +65536)
  const int koff0 = (lg * 16) ^ swz;
  const int koff1 = (64 + lg * 16) ^ swz;

#define READ_A8(dst_, c_, ko_)                                                 \
    _Pragma("unroll")                                                          \
    for (int mi_ = 0; mi_ < 8; ++mi_)                                          \
      dst_[mi_] = *(const bf16x8*)(S + (c_) * 32768 + arow + (mi_ >> 2) * 8192 \
                                   + (mi_ & 3) * 2048 + (ko_));
#define READ_B4(dst_, c_, ko_)                                                 \
    _Pragma("unroll")                                                          \
    for (int ni_ = 0; ni_ < 4; ++ni_)                                          \
      dst_[ni_] = *(const bf16x8*)(S + 65536 + (c_) * 32768 + brow +           \
                                   ni_ * 2048 + (ko_));
#define MFMA_SET(xa_, xb_) do { __builtin_amdgcn_s_setprio(1);                 \
    _Pragma("unroll")                                                          \
    for (int mi_ = 0; mi_ < 8; ++mi_)                                          \
      _Pragma("unroll")                                                        \
      for (int ni_ = 0; ni_ < 4; ++ni_)                                        \
        acc[mi_][ni_] = __builtin_amdgcn_mfma_f32_16x16x32_bf16(               \
            xa_[mi_], xb_[ni_], acc[mi_][ni_], 0, 0, 0);                       \
    __builtin_amdgcn_s_setprio(0); } while (0)

#define SCHED() __builtin_amdgcn_sched_barrier(0)
#define SBAR() do { SCHED(); __builtin_amdgcn_s_barrier(); SCHED(); } while (0)
#define LGKM0() do { asm volatile("s_waitcnt lgkmcnt(0)" ::: "memory"); SCHED(); } while (0)
#define VM0() do { asm volatile("s_waitcnt vmcnt(0)" ::: "memory"); SCHED(); } while (0)

  bf16x8 Aa[8], Ab[4], Ba[8], Bb[4];

  // prologue: kt0 -> buf0, kt1 -> buf1 (16 loads); wait kt0's 8; sync
  STAGE_FULL(0, 0);
  STAGE_FULL(1, 1);
  asm volatile("s_waitcnt vmcnt(8)" ::: "memory");
  SCHED();
  __builtin_amdgcn_s_barrier();
  SCHED();

  // ---- tile 0 (buf0), peeled: no held set yet ----
  READ_A8(Aa, 0, koff0); READ_B4(Ab, 0, koff0);
  SCHED();
  READ_A8(Ba, 0, koff1); READ_B4(Bb, 0, koff1);
  SCHED();
  MFMA_SET(Aa, Ab);         // compiler inserts counted lgkm wait (12 outstanding)
  SCHED();
  LGKM0();
  SBAR();                   // release buf0
  VM0();                    // retires kt1 loads (issued in prologue)
  STAGE_FULL(0, 2);
  SBAR();                   // arrival buf1
  // held: Ba/Bb = kh1 of tile 0 (not yet MFMA'd)

  // ---- steady tiles: READ kh0 | MFMA(held kh1) | READ kh1 | MFMA(kh0) ----
#define KT_STEADY(kt_, c_, st_) do {                                           \
    READ_A8(Aa, c_, koff0); READ_B4(Ab, c_, koff0);                            \
    SCHED();                                                                   \
    MFMA_SET(Ba, Bb);       /* held set: register-only, no wait */             \
    SCHED();                                                                   \
    READ_A8(Ba, c_, koff1); READ_B4(Bb, c_, koff1);                            \
    SCHED();                                                                   \
    MFMA_SET(Aa, Ab);       /* auto counted lgkm wait for Aa/Ab */             \
    SCHED();                                                                   \
    LGKM0();                /* all buf-c reads complete */                     \
    SBAR();                 /* release buf c */                                \
    VM0();                  /* retires prev tile's stage (1 tile of cover) */  \
    if (st_) STAGE_FULL(c_, (kt_) + 2);                                        \
    SBAR();                 /* arrival buf c^1 */                              \
  } while (0)

  #pragma unroll 1
  for (int it = 0; it < 14; ++it) {
    KT_STEADY(2 * it + 1, 1, 1);
    KT_STEADY(2 * it + 2, 0, 1);
  }
  KT_STEADY(29, 1, 1);      // stages kt31 -> buf1
  KT_STEADY(30, 0, 0);      // no stage; vmcnt retires kt31's loads
  // ---- tile 31 (buf1), peeled: no release/stage/arrival ----
  READ_A8(Aa, 1, koff0); READ_B4(Ab, 1, koff0);
  SCHED();
  MFMA_SET(Ba, Bb);
  SCHED();
  READ_A8(Ba, 1, koff1); READ_B4(Bb, 1, koff1);
  SCHED();
  MFMA_SET(Aa, Ab);
  SCHED();
  MFMA_SET(Ba, Bb);
#undef KT_STEADY
#undef MFMA_SET
#undef READ_A8
#undef READ_B4
#undef STAGE_FULL
#undef STAGE_A
#undef STAGE_B

  // epilogue: d2 = x2[m] + p2[p] - 2*dot ; per-wave 64-col window, <=2 batches
  const int wm_base = m0 + wn * 64;
  const int b_lo = wm_base / 196;
  int b_hi = (wm_base + 63) / 196;
  if (b_hi > 31) b_hi = 31;
  const bool wave_ok = (b_lo < 32);
  float x2v[4];
  int seg0[4];
  #pragma unroll
  for (int ni = 0; ni < 4; ++ni) {
    const int m = wm_base + ni * 16 + lr;  // D col = lane&15
    x2v[ni] = x2[m];
    seg0[ni] = ((m / 196) == b_lo);
  }
  const float INF = __uint_as_float(INF_BITS);
  #pragma unroll
  for (int mi = 0; mi < 8; ++mi) {
    const int prow = p0 + wp * 128 + mi * 16 + 4 * lg;  // D row = 4*(lane>>4)+j
    #pragma unroll
    for (int j = 0; j < 4; ++j) {
      const int p = prow + j;
      const float pp = p2[p];
      float ma = INF, mb = INF;
      #pragma unroll
      for (int ni = 0; ni < 4; ++ni) {
        const float d2 = x2v[ni] + pp - 2.f * acc[mi][ni][j];
        ma = fminf(ma, seg0[ni] ? d2 : INF);
        mb = fminf(mb, seg0[ni] ? INF : d2);
      }
      #pragma unroll
      for (int off = 1; off < 16; off <<= 1) {
        ma = fminf(ma, __shfl_xor(ma, off));
        mb = fminf(mb, __shfl_xor(mb, off));
      }
      if (lr == 0 && p < 2000 && wave_ok) {
        atomicMin(&outu[6400 + b_lo * 2000 + p], __float_as_uint(fmaxf(ma, 0.f)));
        if (b_hi != b_lo)
          atomicMin(&outu[6400 + b_hi * 2000 + p], __float_as_uint(fmaxf(mb, 0.f)));
      }
    }
  }
}

// ---- post: d = sqrt(max(d2,1e-12)) in place; sim -> simbuf ----
__global__ void k_post(float* __restrict__ out, float* __restrict__ simbuf) {
  int i = blockIdx.x * blockDim.x + threadIdx.x;
  if (i >= 64000) return;
  float d2 = out[6400 + i];
  float d = sqrtf(fmaxf(d2, 1e-12f));
  out[6400 + i] = d;
  simbuf[i] = logf((d + 1.0f) / (d + 1e-7f));
}

// ---- scores: one wave per (b, class) pair ----
__global__ __launch_bounds__(256) void k_scores(const float* __restrict__ fc_w,
                                                const float* __restrict__ simbuf,
                                                float* __restrict__ out) {
  const int id = blockIdx.x * 4 + (threadIdx.x >> 6);  // 0..6399
  const int lane = threadIdx.x & 63;
  const int b = id / 200;
  const int c = id - b * 200;
  const f32x4* sv = (const f32x4*)(simbuf + (size_t)b * 2000);
  const f32x4* wv = (const f32x4*)(fc_w + (size_t)c * 2000);
  float s = 0.f;
  #pragma unroll
  for (int it = 0; it < 8; ++it) {
    int i = lane + it * 64;
    if (i < 500) {
      f32x4 a = sv[i], w4 = wv[i];
      s += a.x * w4.x + a.y * w4.y + a.z * w4.z + a.w * w4.w;
    }
  }
  #pragma unroll
  for (int off = 32; off; off >>= 1) s += __shfl_xor(s, off);
  if (lane == 0) out[b * 200 + c] = s;
}

extern "C" void kernel_launch(void* const* d_in, const int* in_sizes, int n_in,
                              void* d_out, int out_size, void* d_ws, size_t ws_size,
                              hipStream_t stream) {
  const float* x      = (const float*)d_in[0];  // (32, 2048, 14, 14) f32
  const float* protos = (const float*)d_in[1];  // (1, 2000, 2048) f32
  const float* fc_w   = (const float*)d_in[2];  // (200, 2000) f32
  float* out = (float*)d_out;                   // 6400 scores + 64000 min-dists

  char* wsb = (char*)d_ws;
  unsigned short* pT = (unsigned short*)wsb;              // 2048*4096B  = 8388608
  unsigned short* xT = (unsigned short*)(wsb + 8388608);  // 6400*4096B  = 26214400
  float* p2   = (float*)(wsb + 34603008);                 // 2048 f32
  float* x2   = (float*)(wsb + 34611200);                 // 6400 f32 (pad +inf)
  float* x2p  = (float*)(wsb + 34636800);                 // 32*6272 f32
  float* simb = (float*)(wsb + 34636800);                 // aliases x2p (dead after k_x2r)

  k_prep_p<<<2048, 256, 0, stream>>>(protos, pT, p2, (unsigned int*)d_out);
  k_prep_x<<<dim3(32, 33), 256, 0, stream>>>(x, xT, x2p, x2);
  k_x2r<<<25, 256, 0, stream>>>(x2p, x2);
  k_main<<<200, 512, 0, stream>>>(pT, xT, p2, x2, (unsigned int*)d_out);
  k_post<<<250, 256, 0, stream>>>(out, simb);
  k_scores<<<1600, 256, 0, stream>>>(fc_w, simb, out);
}

// Round 12
// 158.799 us; speedup vs baseline: 1.0019x; 1.0019x over previous
//
#include <hip/hip_runtime.h>

#define INF_BITS 0x7F800000u
#define AS1 __attribute__((address_space(1)))
#define AS3 __attribute__((address_space(3)))

typedef float f32x4 __attribute__((ext_vector_type(4)));
typedef __bf16 bf16x8 __attribute__((ext_vector_type(8)));
typedef unsigned short u16x4 __attribute__((ext_vector_type(4)));
typedef unsigned short u16x8 __attribute__((ext_vector_type(8)));
typedef unsigned int u32x4 __attribute__((ext_vector_type(4)));

static __device__ __forceinline__ unsigned short f2bf(float f) {
  unsigned int u = __float_as_uint(f);
  return (unsigned short)((u + 0x7FFFu + ((u >> 16) & 1u)) >> 16);  // RTNE
}

// ---- protos (2000x2048 f32) -> pT (2048x2048 bf16, pad rows zero) + p2 ----
// also initializes out's min-distance region to +inf (blocks 0..249)
__global__ __launch_bounds__(256) void k_prep_p(const float* __restrict__ protos,
                                                unsigned short* __restrict__ pT,
                                                float* __restrict__ p2,
                                                unsigned int* __restrict__ outu) {
  const int row = blockIdx.x;   // 2048
  const int tid = threadIdx.x;  // 256
  const int gi = row * 256 + tid;
  if (gi < 64000) outu[6400 + gi] = INF_BITS;
  __shared__ float red[4];
  float s = 0.f;
  u16x8 h = (u16x8){0, 0, 0, 0, 0, 0, 0, 0};
  if (row < 2000) {
    const float* src = protos + (size_t)row * 2048 + tid * 8;
    f32x4 a = *(const f32x4*)src;
    f32x4 c = *(const f32x4*)(src + 4);
    h = (u16x8){f2bf(a.x), f2bf(a.y), f2bf(a.z), f2bf(a.w),
                f2bf(c.x), f2bf(c.y), f2bf(c.z), f2bf(c.w)};
    s = a.x * a.x + a.y * a.y + a.z * a.z + a.w * a.w +
        c.x * c.x + c.y * c.y + c.z * c.z + c.w * c.w;
  }
  *(u16x8*)(pT + (size_t)row * 2048 + tid * 8) = h;
  #pragma unroll
  for (int off = 32; off; off >>= 1) s += __shfl_xor(s, off);
  if ((tid & 63) == 0) red[tid >> 6] = s;
  __syncthreads();
  if (tid == 0) p2[row] = red[0] + red[1] + red[2] + red[3];
}

// ---- x (b,k,n) f32 -> xT[(b*196+n)*2048+k] bf16 + x2 partials ----
__global__ __launch_bounds__(256) void k_prep_x(const float* __restrict__ x,
                                                unsigned short* __restrict__ xT,
                                                float* __restrict__ x2p,
                                                float* __restrict__ x2) {
  const int kt = blockIdx.x;  // 32
  const int b  = blockIdx.y;  // 33: b==32 -> padding work
  const int tid = threadIdx.x;
  if (b == 32) {
    u32x4* pad = (u32x4*)(xT + (size_t)6272 * 2048);
    #pragma unroll
    for (int j = tid; j < 1024; j += 256)
      pad[kt * 1024 + j] = (u32x4){0u, 0u, 0u, 0u};
    if (kt == 0 && tid < 128) x2[6272 + tid] = __uint_as_float(INF_BITS);
    return;
  }
  __shared__ unsigned short Ls[64][204];  // stride 204: 8B-aligned u16x4 stores
  const float* src = x + ((size_t)b * 2048 + (size_t)kt * 64) * 196;
  for (int idx = tid; idx < 3136; idx += 256) {
    const int kk = idx / 49, c4 = idx - kk * 49;
    f32x4 v = *(const f32x4*)(src + (size_t)kk * 196 + c4 * 4);
    *(u16x4*)&Ls[kk][c4 * 4] = (u16x4){f2bf(v.x), f2bf(v.y), f2bf(v.z), f2bf(v.w)};
  }
  __syncthreads();
  if (tid < 196) {
    float s = 0.f;
    #pragma unroll
    for (int j = 0; j < 64; ++j) {
      float v = __uint_as_float((unsigned int)Ls[j][tid] << 16);
      s += v * v;
    }
    x2p[kt * 6272 + b * 196 + tid] = s;
  }
  unsigned short* dstb = xT + (size_t)b * 196 * 2048 + kt * 64;
  for (int idx = tid; idx < 1568; idx += 256) {
    const int n = idx >> 3, q = idx & 7;
    const int k0 = q * 8;
    u32x4 v;
    v.x = (unsigned int)Ls[k0 + 0][n] | ((unsigned int)Ls[k0 + 1][n] << 16);
    v.y = (unsigned int)Ls[k0 + 2][n] | ((unsigned int)Ls[k0 + 3][n] << 16);
    v.z = (unsigned int)Ls[k0 + 4][n] | ((unsigned int)Ls[k0 + 5][n] << 16);
    v.w = (unsigned int)Ls[k0 + 6][n] | ((unsigned int)Ls[k0 + 7][n] << 16);
    *(u32x4*)(dstb + (size_t)n * 2048 + k0) = v;
  }
}

__global__ void k_x2r(const float* __restrict__ x2p, float* __restrict__ x2) {
  int i = blockIdx.x * blockDim.x + threadIdx.x;
  if (i >= 6272) return;
  float s = 0.f;
  #pragma unroll
  for (int c = 0; c < 32; ++c) s += x2p[c * 6272 + i];
  x2[i] = s;
}

// ---- main GEMM: 256x256 tile, BK=64, 8 waves; cross-half-tile read-ahead.
// launch_bounds(512,1): grid=200 < 256 CUs means 1 block/CU regardless; the
// relaxed bound doubles the register budget so the two held fragment sets
// (96 VGPRs) stay in registers (r11's ",2" caused scratch spill: 37MB writes).
__global__ __launch_bounds__(512, 1) void k_main(
    const unsigned short* __restrict__ pT, const unsigned short* __restrict__ xT,
    const float* __restrict__ p2, const float* __restrict__ x2,
    unsigned int* __restrict__ outu) {
  const int orig = blockIdx.x;
  const int wgid = (orig & 7) * 25 + (orig >> 3);
  const int ptpair = wgid / 50;
  const int rem = wgid - ptpair * 50;
  const int ptile = ptpair * 2 + (rem & 1);  // 0..7
  const int mtile = rem >> 1;                // 0..24
  const int p0 = ptile * 256;
  const int m0 = mtile * 256;
  const int tid = threadIdx.x;
  const int lane = tid & 63;
  const int w = tid >> 6;   // 8 waves
  const int wp = w >> 2;    // A half (128 rows)
  const int wn = w & 3;     // B quarter (64 rows)
  const int lr = lane & 15;
  const int lg = lane >> 4;

  __shared__ __align__(16) char S[131072];  // A[2]:0..64K, B[2]:64K..128K

  f32x4 acc[8][4];
  #pragma unroll
  for (int mi = 0; mi < 8; ++mi)
    #pragma unroll
    for (int ni = 0; ni < 4; ++ni)
      acc[mi][ni] = (f32x4){0.f, 0.f, 0.f, 0.f};

  const int rowbase = tid >> 3;                       // 0..63
  const int chunk = (tid & 7) ^ (rowbase & 7);        // involution
  const char* gA = (const char*)pT + (size_t)(p0 + rowbase) * 4096 + chunk * 16;
  const char* gB = (const char*)xT + (size_t)(m0 + rowbase) * 4096 + chunk * 16;
  const int wbase = w * 1024;

#define STAGE_A(c_, kt_, h_) do {                                              \
    const char* s_ = gA + (size_t)((h_) * 128 * 4096) + (size_t)(kt_) * 128;   \
    _Pragma("unroll")                                                          \
    for (int j_ = 0; j_ < 2; ++j_)                                             \
      __builtin_amdgcn_global_load_lds(                                        \
          (const AS1 void*)(s_ + (size_t)j_ * 64 * 4096),                      \
          (AS3 void*)(S + (c_) * 32768 + (h_) * 16384 + j_ * 8192 + wbase),    \
          16, 0, 0);                                                           \
  } while (0)
#define STAGE_B(c_, kt_, h_) do {                                              \
    const char* s_ = gB + (size_t)((h_) * 128 * 4096) + (size_t)(kt_) * 128;   \
    _Pragma("unroll")                                                          \
    for (int j_ = 0; j_ < 2; ++j_)                                             \
      __builtin_amdgcn_global_load_lds(                                        \
          (const AS1 void*)(s_ + (size_t)j_ * 64 * 4096),                      \
          (AS3 void*)(S + 65536 + (c_) * 32768 + (h_) * 16384 + j_ * 8192 + wbase), \
          16, 0, 0);                                                           \
  } while (0)
#define STAGE_FULL(c_, kt_) do {                                               \
    STAGE_A(c_, kt_, 0); STAGE_A(c_, kt_, 1);                                  \
    STAGE_B(c_, kt_, 0); STAGE_B(c_, kt_, 1); } while (0)

  const int swz = ((lr & 7) << 4);
  const int arow = (wp * 128 + lr) * 128;        // + (mi>>2)*8192 + (mi&3)*2048
  const int brow = (wn * 64 + lr) * 128;         // + ni*2048 (B region +65536)
  const int koff0 = (lg * 16) ^ swz;
  const int koff1 = (64 + lg * 16) ^ swz;

#define READ_A8(dst_, c_, ko_)                                                 \
    _Pragma("unroll")                                                          \
    for (int mi_ = 0; mi_ < 8; ++mi_)                                          \
      dst_[mi_] = *(const bf16x8*)(S + (c_) * 32768 + arow + (mi_ >> 2) * 8192 \
                                   + (mi_ & 3) * 2048 + (ko_));
#define READ_B4(dst_, c_, ko_)                                                 \
    _Pragma("unroll")                                                          \
    for (int ni_ = 0; ni_ < 4; ++ni_)                                          \
      dst_[ni_] = *(const bf16x8*)(S + 65536 + (c_) * 32768 + brow +           \
                                   ni_ * 2048 + (ko_));
#define MFMA_SET(xa_, xb_) do { __builtin_amdgcn_s_setprio(1);                 \
    _Pragma("unroll")                                                          \
    for (int mi_ = 0; mi_ < 8; ++mi_)                                          \
      _Pragma("unroll")                                                        \
      for (int ni_ = 0; ni_ < 4; ++ni_)                                        \
        acc[mi_][ni_] = __builtin_amdgcn_mfma_f32_16x16x32_bf16(               \
            xa_[mi_], xb_[ni_], acc[mi_][ni_], 0, 0, 0);                       \
    __builtin_amdgcn_s_setprio(0); } while (0)

#define SCHED() __builtin_amdgcn_sched_barrier(0)
#define SBAR() do { SCHED(); __builtin_amdgcn_s_barrier(); SCHED(); } while (0)
#define LGKM0() do { asm volatile("s_waitcnt lgkmcnt(0)" ::: "memory"); SCHED(); } while (0)
#define VM0() do { asm volatile("s_waitcnt vmcnt(0)" ::: "memory"); SCHED(); } while (0)

  bf16x8 Aa[8], Ab[4], Ba[8], Bb[4];

  // prologue: kt0 -> buf0, kt1 -> buf1 (16 loads); wait kt0's 8; sync
  STAGE_FULL(0, 0);
  STAGE_FULL(1, 1);
  asm volatile("s_waitcnt vmcnt(8)" ::: "memory");
  SCHED();
  __builtin_amdgcn_s_barrier();
  SCHED();

  // ---- tile 0 (buf0), peeled: no held set yet ----
  READ_A8(Aa, 0, koff0); READ_B4(Ab, 0, koff0);
  SCHED();
  READ_A8(Ba, 0, koff1); READ_B4(Bb, 0, koff1);
  SCHED();
  MFMA_SET(Aa, Ab);         // compiler inserts counted lgkm wait (12 outstanding)
  SCHED();
  LGKM0();
  SBAR();                   // release buf0
  VM0();                    // retires kt1 loads (issued in prologue)
  STAGE_FULL(0, 2);
  SBAR();                   // arrival buf1
  // held: Ba/Bb = kh1 of tile 0 (not yet MFMA'd)

  // ---- steady tiles: READ kh0 | MFMA(held kh1) | READ kh1 | MFMA(kh0) ----
#define KT_STEADY(kt_, c_, st_) do {                                           \
    READ_A8(Aa, c_, koff0); READ_B4(Ab, c_, koff0);                            \
    SCHED();                                                                   \
    MFMA_SET(Ba, Bb);       /* held set: register-only, no wait */             \
    SCHED();                                                                   \
    READ_A8(Ba, c_, koff1); READ_B4(Bb, c_, koff1);                            \
    SCHED();                                                                   \
    MFMA_SET(Aa, Ab);       /* auto counted lgkm wait for Aa/Ab */             \
    SCHED();                                                                   \
    LGKM0();                /* all buf-c reads complete */                     \
    SBAR();                 /* release buf c */                                \
    VM0();                  /* retires prev tile's stage (1 tile of cover) */  \
    if (st_) STAGE_FULL(c_, (kt_) + 2);                                        \
    SBAR();                 /* arrival buf c^1 */                              \
  } while (0)

  #pragma unroll 1
  for (int it = 0; it < 14; ++it) {
    KT_STEADY(2 * it + 1, 1, 1);
    KT_STEADY(2 * it + 2, 0, 1);
  }
  KT_STEADY(29, 1, 1);      // stages kt31 -> buf1
  KT_STEADY(30, 0, 0);      // no stage; vmcnt retires kt31's loads
  // ---- tile 31 (buf1), peeled: no release/stage/arrival ----
  READ_A8(Aa, 1, koff0); READ_B4(Ab, 1, koff0);
  SCHED();
  MFMA_SET(Ba, Bb);
  SCHED();
  READ_A8(Ba, 1, koff1); READ_B4(Bb, 1, koff1);
  SCHED();
  MFMA_SET(Aa, Ab);
  SCHED();
  MFMA_SET(Ba, Bb);
#undef KT_STEADY
#undef MFMA_SET
#undef READ_A8
#undef READ_B4
#undef STAGE_FULL
#undef STAGE_A
#undef STAGE_B

  // epilogue: d2 = x2[m] + p2[p] - 2*dot ; per-wave 64-col window, <=2 batches
  const int wm_base = m0 + wn * 64;
  const int b_lo = wm_base / 196;
  int b_hi = (wm_base + 63) / 196;
  if (b_hi > 31) b_hi = 31;
  const bool wave_ok = (b_lo < 32);
  float x2v[4];
  int seg0[4];
  #pragma unroll
  for (int ni = 0; ni < 4; ++ni) {
    const int m = wm_base + ni * 16 + lr;  // D col = lane&15
    x2v[ni] = x2[m];
    seg0[ni] = ((m / 196) == b_lo);
  }
  const float INF = __uint_as_float(INF_BITS);
  #pragma unroll
  for (int mi = 0; mi < 8; ++mi) {
    const int prow = p0 + wp * 128 + mi * 16 + 4 * lg;  // D row = 4*(lane>>4)+j
    #pragma unroll
    for (int j = 0; j < 4; ++j) {
      const int p = prow + j;
      const float pp = p2[p];
      float ma = INF, mb = INF;
      #pragma unroll
      for (int ni = 0; ni < 4; ++ni) {
        const float d2 = x2v[ni] + pp - 2.f * acc[mi][ni][j];
        ma = fminf(ma, seg0[ni] ? d2 : INF);
        mb = fminf(mb, seg0[ni] ? INF : d2);
      }
      #pragma unroll
      for (int off = 1; off < 16; off <<= 1) {
        ma = fminf(ma, __shfl_xor(ma, off));
        mb = fminf(mb, __shfl_xor(mb, off));
      }
      if (lr == 0 && p < 2000 && wave_ok) {
        atomicMin(&outu[6400 + b_lo * 2000 + p], __float_as_uint(fmaxf(ma, 0.f)));
        if (b_hi != b_lo)
          atomicMin(&outu[6400 + b_hi * 2000 + p], __float_as_uint(fmaxf(mb, 0.f)));
      }
    }
  }
}

// ---- post: d = sqrt(max(d2,1e-12)) in place; sim -> simbuf ----
__global__ void k_post(float* __restrict__ out, float* __restrict__ simbuf) {
  int i = blockIdx.x * blockDim.x + threadIdx.x;
  if (i >= 64000) return;
  float d2 = out[6400 + i];
  float d = sqrtf(fmaxf(d2, 1e-12f));
  out[6400 + i] = d;
  simbuf[i] = logf((d + 1.0f) / (d + 1e-7f));
}

// ---- scores: one wave per (b, class) pair ----
__global__ __launch_bounds__(256) void k_scores(const float* __restrict__ fc_w,
                                                const float* __restrict__ simbuf,
                                                float* __restrict__ out) {
  const int id = blockIdx.x * 4 + (threadIdx.x >> 6);  // 0..6399
  const int lane = threadIdx.x & 63;
  const int b = id / 200;
  const int c = id - b * 200;
  const f32x4* sv = (const f32x4*)(simbuf + (size_t)b * 2000);
  const f32x4* wv = (const f32x4*)(fc_w + (size_t)c * 2000);
  float s = 0.f;
  #pragma unroll
  for (int it = 0; it < 8; ++it) {
    int i = lane + it * 64;
    if (i < 500) {
      f32x4 a = sv[i], w4 = wv[i];
      s += a.x * w4.x + a.y * w4.y + a.z * w4.z + a.w * w4.w;
    }
  }
  #pragma unroll
  for (int off = 32; off; off >>= 1) s += __shfl_xor(s, off);
  if (lane == 0) out[b * 200 + c] = s;
}

extern "C" void kernel_launch(void* const* d_in, const int* in_sizes, int n_in,
                              void* d_out, int out_size, void* d_ws, size_t ws_size,
                              hipStream_t stream) {
  const float* x      = (const float*)d_in[0];  // (32, 2048, 14, 14) f32
  const float* protos = (const float*)d_in[1];  // (1, 2000, 2048) f32
  const float* fc_w   = (const float*)d_in[2];  // (200, 2000) f32
  float* out = (float*)d_out;                   // 6400 scores + 64000 min-dists

  char* wsb = (char*)d_ws;
  unsigned short* pT = (unsigned short*)wsb;              // 2048*4096B  = 8388608
  unsigned short* xT = (unsigned short*)(wsb + 8388608);  // 6400*4096B  = 26214400
  float* p2   = (float*)(wsb + 34603008);                 // 2048 f32
  float* x2   = (float*)(wsb + 34611200);                 // 6400 f32 (pad +inf)
  float* x2p  = (float*)(wsb + 34636800);                 // 32*6272 f32
  float* simb = (float*)(wsb + 34636800);                 // aliases x2p (dead after k_x2r)

  k_prep_p<<<2048, 256, 0, stream>>>(protos, pT, p2, (unsigned int*)d_out);
  k_prep_x<<<dim3(32, 33), 256, 0, stream>>>(x, xT, x2p, x2);
  k_x2r<<<25, 256, 0, stream>>>(x2p, x2);
  k_main<<<200, 512, 0, stream>>>(pT, xT, p2, x2, (unsigned int*)d_out);
  k_post<<<250, 256, 0, stream>>>(out, simb);
  k_scores<<<1600, 256, 0, stream>>>(fc_w, simb, out);
}

// Round 14
// 99.837 us; speedup vs baseline: 1.5935x; 1.5906x over previous
//
#include <hip/hip_runtime.h>

#define INF_BITS 0x7F800000u
#define AS1 __attribute__((address_space(1)))
#define AS3 __attribute__((address_space(3)))

typedef float f32x4 __attribute__((ext_vector_type(4)));
typedef unsigned int u32x2 __attribute__((ext_vector_type(2)));
typedef unsigned int u32x4 __attribute__((ext_vector_type(4)));

template <int SEL>
static __device__ __forceinline__ float dq8(unsigned int w) {
  return __builtin_amdgcn_cvt_f32_fp8((int)w, SEL);
}

// ---- protos (2000x2048 f32) -> pTf (2048x2048 fp8 e4m3, pad zero) + p2 ----
// p2 computed from the QUANTIZED values (so d^2 = ||xq-pq||^2 exactly).
// also initializes out's min-distance region to +inf.
__global__ __launch_bounds__(256) void k_prep_p(const float* __restrict__ protos,
                                                unsigned char* __restrict__ pTf,
                                                float* __restrict__ p2,
                                                unsigned int* __restrict__ outu) {
  const int row = blockIdx.x;   // 2048
  const int tid = threadIdx.x;  // 256
  const int gi = row * 256 + tid;
  if (gi < 64000) outu[6400 + gi] = INF_BITS;
  __shared__ float red[4];
  float s = 0.f;
  unsigned int w0 = 0u, w1 = 0u;
  if (row < 2000) {
    const float* src = protos + (size_t)row * 2048 + tid * 8;
    f32x4 a = *(const f32x4*)src;
    f32x4 c = *(const f32x4*)(src + 4);
    w0 = (unsigned int)__builtin_amdgcn_cvt_pk_fp8_f32(a.x, a.y, 0, false);
    w0 = (unsigned int)__builtin_amdgcn_cvt_pk_fp8_f32(a.z, a.w, (int)w0, true);
    w1 = (unsigned int)__builtin_amdgcn_cvt_pk_fp8_f32(c.x, c.y, 0, false);
    w1 = (unsigned int)__builtin_amdgcn_cvt_pk_fp8_f32(c.z, c.w, (int)w1, true);
    float q;
    q = dq8<0>(w0); s += q * q;
    q = dq8<1>(w0); s += q * q;
    q = dq8<2>(w0); s += q * q;
    q = dq8<3>(w0); s += q * q;
    q = dq8<0>(w1); s += q * q;
    q = dq8<1>(w1); s += q * q;
    q = dq8<2>(w1); s += q * q;
    q = dq8<3>(w1); s += q * q;
  }
  *(u32x2*)(pTf + (size_t)row * 2048 + tid * 8) = (u32x2){w0, w1};
  #pragma unroll
  for (int off = 32; off; off >>= 1) s += __shfl_xor(s, off);
  if ((tid & 63) == 0) red[tid >> 6] = s;
  __syncthreads();
  if (tid == 0) p2[row] = red[0] + red[1] + red[2] + red[3];
}

// ---- x (b,k,n) f32 -> xTf[(b*196+n)*2048+k] fp8 + x2 partials (quantized) ----
__global__ __launch_bounds__(256) void k_prep_x(const float* __restrict__ x,
                                                unsigned char* __restrict__ xTf,
                                                float* __restrict__ x2p,
                                                float* __restrict__ x2) {
  const int kt = blockIdx.x;  // 32 (64-k chunks of source)
  const int b  = blockIdx.y;  // 33: b==32 -> padding work
  const int tid = threadIdx.x;
  if (b == 32) {
    // zero xTf rows 6272..6399 (128 * 2048 B = 16384 u32x4) over 32 blocks
    u32x4* pad = (u32x4*)(xTf + (size_t)6272 * 2048);
    #pragma unroll
    for (int j = tid; j < 512; j += 256)
      pad[kt * 512 + j] = (u32x4){0u, 0u, 0u, 0u};
    if (kt == 0 && tid < 128) x2[6272 + tid] = __uint_as_float(INF_BITS);
    return;
  }
  __shared__ unsigned char Ls[64][208];  // fp8 bytes; stride 208 (4B-aligned)
  const float* src = x + ((size_t)b * 2048 + (size_t)kt * 64) * 196;
  for (int idx = tid; idx < 3136; idx += 256) {
    const int kk = idx / 49, c4 = idx - kk * 49;
    f32x4 v = *(const f32x4*)(src + (size_t)kk * 196 + c4 * 4);
    unsigned int w = (unsigned int)__builtin_amdgcn_cvt_pk_fp8_f32(v.x, v.y, 0, false);
    w = (unsigned int)__builtin_amdgcn_cvt_pk_fp8_f32(v.z, v.w, (int)w, true);
    *(unsigned int*)&Ls[kk][c4 * 4] = w;
  }
  __syncthreads();
  if (tid < 196) {  // x2 partial from quantized values (column tid)
    float s = 0.f;
    #pragma unroll
    for (int j = 0; j < 64; ++j) {
      float v = dq8<0>((unsigned int)Ls[j][tid]);
      s += v * v;
    }
    x2p[kt * 6272 + b * 196 + tid] = s;
  }
  // transposed write-out: per n, 4 x u32x4 (16B) covering this kt's 64 k
  unsigned char* dstb = xTf + (size_t)b * 196 * 2048 + kt * 64;
  for (int idx = tid; idx < 784; idx += 256) {
    const int n = idx >> 2, q = idx & 3;
    const int k0 = q * 16;
    u32x4 v;
    #pragma unroll
    for (int j = 0; j < 4; ++j) {
      v[j] = (unsigned int)Ls[k0 + 4 * j + 0][n] |
             ((unsigned int)Ls[k0 + 4 * j + 1][n] << 8) |
             ((unsigned int)Ls[k0 + 4 * j + 2][n] << 16) |
             ((unsigned int)Ls[k0 + 4 * j + 3][n] << 24);
    }
    *(u32x4*)(dstb + (size_t)n * 2048 + k0) = v;
  }
}

__global__ void k_x2r(const float* __restrict__ x2p, float* __restrict__ x2) {
  int i = blockIdx.x * blockDim.x + threadIdx.x;
  if (i >= 6272) return;
  float s = 0.f;
  #pragma unroll
  for (int c = 0; c < 32; ++c) s += x2p[c * 6272 + i];
  x2[i] = s;
}

// ---- main GEMM: fp8 e4m3, 256x256 tile, BK=128 (same 128B/row geometry as
// the bf16 BK=64 kernel), 8 waves, r5's proven 4-phase schedule, 16 K-tiles ----
__global__ __launch_bounds__(512, 2) void k_main(
    const unsigned char* __restrict__ pTf, const unsigned char* __restrict__ xTf,
    const float* __restrict__ p2, const float* __restrict__ x2,
    unsigned int* __restrict__ outu) {
  const int orig = blockIdx.x;
  const int wgid = (orig & 7) * 25 + (orig >> 3);
  const int ptpair = wgid / 50;
  const int rem = wgid - ptpair * 50;
  const int ptile = ptpair * 2 + (rem & 1);  // 0..7
  const int mtile = rem >> 1;                // 0..24
  const int p0 = ptile * 256;
  const int m0 = mtile * 256;
  const int tid = threadIdx.x;
  const int lane = tid & 63;
  const int w = tid >> 6;   // 8 waves
  const int wp = w >> 2;    // A half (128 rows)
  const int wn = w & 3;     // B quarter (64 rows)
  const int lr = lane & 15;
  const int lg = lane >> 4;

  __shared__ __align__(16) char S[131072];  // A[2]:0..64K, B[2]:64K..128K

  f32x4 acc[8][4];
  #pragma unroll
  for (int mi = 0; mi < 8; ++mi)
    #pragma unroll
    for (int ni = 0; ni < 4; ++ni)
      acc[mi][ni] = (f32x4){0.f, 0.f, 0.f, 0.f};

  const int rowbase = tid >> 3;                       // 0..63
  const int chunk = (tid & 7) ^ (rowbase & 7);        // involution
  const char* gA = (const char*)pTf + (size_t)(p0 + rowbase) * 2048 + chunk * 16;
  const char* gB = (const char*)xTf + (size_t)(m0 + rowbase) * 2048 + chunk * 16;
  const int wbase = w * 1024;

#define STAGE_A(c_, kt_, h_) do {                                              \
    const char* s_ = gA + (size_t)((h_) * 128 * 2048) + (size_t)(kt_) * 128;   \
    _Pragma("unroll")                                                          \
    for (int j_ = 0; j_ < 2; ++j_)                                             \
      __builtin_amdgcn_global_load_lds(                                        \
          (const AS1 void*)(s_ + (size_t)j_ * 64 * 2048),                      \
          (AS3 void*)(S + (c_) * 32768 + (h_) * 16384 + j_ * 8192 + wbase),    \
          16, 0, 0);                                                           \
  } while (0)
#define STAGE_B(c_, kt_, h_) do {                                              \
    const char* s_ = gB + (size_t)((h_) * 128 * 2048) + (size_t)(kt_) * 128;   \
    _Pragma("unroll")                                                          \
    for (int j_ = 0; j_ < 2; ++j_)                                             \
      __builtin_amdgcn_global_load_lds(                                        \
          (const AS1 void*)(s_ + (size_t)j_ * 64 * 2048),                      \
          (AS3 void*)(S + 65536 + (c_) * 32768 + (h_) * 16384 + j_ * 8192 + wbase), \
          16, 0, 0);                                                           \
  } while (0)

  // fragment addressing: frag for k-step ks (k in [32ks,32ks+32), lane k-group
  // lg) is 8B at logical row byte ks*32 + lg*8; stored chunk-XOR-swizzled:
  // chunk = (2ks + (lg>>1)) ^ (row&7), within-chunk byte = (lg&1)*8.
  const int arow = (wp * 128 + lr) * 128;   // + (hf*4+mi)*2048 + koff[ks]
  const int brow = (wn * 64 + lr) * 128;    // + ni*2048 (B region +65536)
  int koff[4];
  #pragma unroll
  for (int ks = 0; ks < 4; ++ks)
    koff[ks] = (((2 * ks + (lg >> 1)) ^ (lr & 7)) << 4) | ((lg & 1) << 3);

#define READ_A(dst_, c_, hf_, kp_)                                             \
    _Pragma("unroll")                                                          \
    for (int ks_ = 0; ks_ < 2; ++ks_)                                          \
      _Pragma("unroll")                                                        \
      for (int mi_ = 0; mi_ < 4; ++mi_)                                        \
        dst_[ks_ * 4 + mi_] = *(const long*)(S + (c_) * 32768 + arow +         \
            ((hf_) * 4 + mi_) * 2048 + koff[(kp_) * 2 + ks_]);
#define READ_B(dst_, c_, kp_)                                                  \
    _Pragma("unroll")                                                          \
    for (int ks_ = 0; ks_ < 2; ++ks_)                                          \
      _Pragma("unroll")                                                        \
      for (int ni_ = 0; ni_ < 4; ++ni_)                                        \
        dst_[ks_ * 4 + ni_] = *(const long*)(S + 65536 + (c_) * 32768 + brow + \
            ni_ * 2048 + koff[(kp_) * 2 + ks_]);

#define PH_BAR() do { __builtin_amdgcn_sched_barrier(0);                       \
    __builtin_amdgcn_s_barrier(); __builtin_amdgcn_sched_barrier(0); } while (0)
#define LGKM0() do { asm volatile("s_waitcnt lgkmcnt(0)" ::: "memory");        \
    __builtin_amdgcn_sched_barrier(0); } while (0)
#define MFMA_Q(mlo_, af_, bf_) do { __builtin_amdgcn_s_setprio(1);             \
    _Pragma("unroll")                                                          \
    for (int ks_ = 0; ks_ < 2; ++ks_)                                          \
      _Pragma("unroll")                                                        \
      for (int mi_ = 0; mi_ < 4; ++mi_)                                        \
        _Pragma("unroll")                                                      \
        for (int ni_ = 0; ni_ < 4; ++ni_)                                      \
          acc[(mlo_) + mi_][ni_] = __builtin_amdgcn_mfma_f32_16x16x32_fp8_fp8( \
              af_[ks_ * 4 + mi_], bf_[ks_ * 4 + ni_], acc[(mlo_) + mi_][ni_],  \
              0, 0, 0);                                                        \
    __builtin_amdgcn_s_setprio(0); } while (0)

  // Per K-tile (BK=128 fp8): r5's 4 phases; stages A[kt+1]h0, A[kt+1]h1,
  // B[kt+2]h0, B[kt+2]h1; single vmcnt(4) at Ph3 retires {B[kt+1], A[kt+1]}.
#define KT_BODY(kt_, c_, sa_, sb_, vm_) do {                                   \
    long alo[8], ahi[8], b01[8], b23[8];                                       \
    READ_A(alo, c_, 0, 0);                                                     \
    READ_B(b01, c_, 0);                                                        \
    if (sa_) STAGE_A((c_) ^ 1, (kt_) + 1, 0);                                  \
    PH_BAR(); LGKM0();                                                         \
    MFMA_Q(0, alo, b01);                                                       \
    PH_BAR();                                                                  \
    READ_A(ahi, c_, 1, 0);                                                     \
    READ_B(b23, c_, 1);                                                        \
    if (sa_) STAGE_A((c_) ^ 1, (kt_) + 1, 1);                                  \
    PH_BAR(); LGKM0();                                                         \
    MFMA_Q(4, ahi, b01);                                                       \
    PH_BAR();                                                                  \
    READ_A(alo, c_, 0, 1);                                                     \
    if (sb_) STAGE_B(c_, (kt_) + 2, 0);                                        \
    PH_BAR(); LGKM0();                                                         \
    MFMA_Q(0, alo, b23);                                                       \
    PH_BAR();                                                                  \
    READ_A(ahi, c_, 1, 1);                                                     \
    if (sb_) STAGE_B(c_, (kt_) + 2, 1);                                        \
    if ((vm_) == 4)      asm volatile("s_waitcnt vmcnt(4)" ::: "memory");      \
    else if ((vm_) == 0) asm volatile("s_waitcnt vmcnt(0)" ::: "memory");      \
    __builtin_amdgcn_sched_barrier(0);                                         \
    PH_BAR(); LGKM0();                                                         \
    MFMA_Q(4, ahi, b23);                                                       \
    PH_BAR();                                                                  \
  } while (0)

  STAGE_B(0, 0, 0); STAGE_B(0, 0, 1);
  STAGE_A(0, 0, 0); STAGE_A(0, 0, 1);
  STAGE_B(1, 1, 0); STAGE_B(1, 1, 1);
  asm volatile("s_waitcnt vmcnt(4)" ::: "memory");
  __builtin_amdgcn_sched_barrier(0);
  __builtin_amdgcn_s_barrier();
  __builtin_amdgcn_sched_barrier(0);

  #pragma unroll 1
  for (int it = 0; it < 7; ++it) {
    KT_BODY(2 * it, 0, 1, 1, 4);
    KT_BODY(2 * it + 1, 1, 1, 1, 4);
  }
  KT_BODY(14, 0, 1, 0, 0);   // stages A[15]; no B[16]; drain all
  KT_BODY(15, 1, 0, 0, -1);  // pure compute
#undef KT_BODY
#undef MFMA_Q
#undef READ_A
#undef READ_B
#undef STAGE_A
#undef STAGE_B

  // epilogue: d2 = x2[m] + p2[p] - 2*dot ; per-wave 64-col window, <=2 batches
  const int wm_base = m0 + wn * 64;
  const int b_lo = wm_base / 196;
  int b_hi = (wm_base + 63) / 196;
  if (b_hi > 31) b_hi = 31;
  const bool wave_ok = (b_lo < 32);
  float x2v[4];
  int seg0[4];
  #pragma unroll
  for (int ni = 0; ni < 4; ++ni) {
    const int m = wm_base + ni * 16 + lr;  // D col = lane&15
    x2v[ni] = x2[m];
    seg0[ni] = ((m / 196) == b_lo);
  }
  const float INF = __uint_as_float(INF_BITS);
  #pragma unroll
  for (int mi = 0; mi < 8; ++mi) {
    const int prow = p0 + wp * 128 + mi * 16 + 4 * lg;  // D row = 4*(lane>>4)+j
    #pragma unroll
    for (int j = 0; j < 4; ++j) {
      const int p = prow + j;
      const float pp = p2[p];
      float ma = INF, mb = INF;
      #pragma unroll
      for (int ni = 0; ni < 4; ++ni) {
        const float d2 = x2v[ni] + pp - 2.f * acc[mi][ni][j];
        ma = fminf(ma, seg0[ni] ? d2 : INF);
        mb = fminf(mb, seg0[ni] ? INF : d2);
      }
      #pragma unroll
      for (int off = 1; off < 16; off <<= 1) {
        ma = fminf(ma, __shfl_xor(ma, off));
        mb = fminf(mb, __shfl_xor(mb, off));
      }
      if (lr == 0 && p < 2000 && wave_ok) {
        atomicMin(&outu[6400 + b_lo * 2000 + p], __float_as_uint(fmaxf(ma, 0.f)));
        if (b_hi != b_lo)
          atomicMin(&outu[6400 + b_hi * 2000 + p], __float_as_uint(fmaxf(mb, 0.f)));
      }
    }
  }
}

// ---- post: d = sqrt(max(d2,1e-12)) in place; sim -> simbuf ----
__global__ void k_post(float* __restrict__ out, float* __restrict__ simbuf) {
  int i = blockIdx.x * blockDim.x + threadIdx.x;
  if (i >= 64000) return;
  float d2 = out[6400 + i];
  float d = sqrtf(fmaxf(d2, 1e-12f));
  out[6400 + i] = d;
  simbuf[i] = logf((d + 1.0f) / (d + 1e-7f));
}

// ---- scores: one wave per (b, class) pair ----
__global__ __launch_bounds__(256) void k_scores(const float* __restrict__ fc_w,
                                                const float* __restrict__ simbuf,
                                                float* __restrict__ out) {
  const int id = blockIdx.x * 4 + (threadIdx.x >> 6);  // 0..6399
  const int lane = threadIdx.x & 63;
  const int b = id / 200;
  const int c = id - b * 200;
  const f32x4* sv = (const f32x4*)(simbuf + (size_t)b * 2000);
  const f32x4* wv = (const f32x4*)(fc_w + (size_t)c * 2000);
  float s = 0.f;
  #pragma unroll
  for (int it = 0; it < 8; ++it) {
    int i = lane + it * 64;
    if (i < 500) {
      f32x4 a = sv[i], w4 = wv[i];
      s += a.x * w4.x + a.y * w4.y + a.z * w4.z + a.w * w4.w;
    }
  }
  #pragma unroll
  for (int off = 32; off; off >>= 1) s += __shfl_xor(s, off);
  if (lane == 0) out[b * 200 + c] = s;
}

extern "C" void kernel_launch(void* const* d_in, const int* in_sizes, int n_in,
                              void* d_out, int out_size, void* d_ws, size_t ws_size,
                              hipStream_t stream) {
  const float* x      = (const float*)d_in[0];  // (32, 2048, 14, 14) f32
  const float* protos = (const float*)d_in[1];  // (1, 2000, 2048) f32
  const float* fc_w   = (const float*)d_in[2];  // (200, 2000) f32
  float* out = (float*)d_out;                   // 6400 scores + 64000 min-dists

  char* wsb = (char*)d_ws;
  unsigned char* pTf = (unsigned char*)wsb;               // 2048*2048 = 4194304
  unsigned char* xTf = (unsigned char*)(wsb + 4194304);   // 6400*2048 = 13107200
  float* p2   = (float*)(wsb + 17301504);                 // 2048 f32
  float* x2   = (float*)(wsb + 17309696);                 // 6400 f32 (pad +inf)
  float* x2p  = (float*)(wsb + 17335296);                 // 32*6272 f32
  float* simb = (float*)(wsb + 17335296);                 // aliases x2p (dead after k_x2r)

  k_prep_p<<<2048, 256, 0, stream>>>(protos, pTf, p2, (unsigned int*)d_out);
  k_prep_x<<<dim3(32, 33), 256, 0, stream>>>(x, xTf, x2p, x2);
  k_x2r<<<25, 256, 0, stream>>>(x2p, x2);
  k_main<<<200, 512, 0, stream>>>(pTf, xTf, p2, x2, (unsigned int*)d_out);
  k_post<<<250, 256, 0, stream>>>(out, simb);
  k_scores<<<1600, 256, 0, stream>>>(fc_w, simb, out);
}

// Round 15
// 87.521 us; speedup vs baseline: 1.8178x; 1.1407x over previous
//
#include <hip/hip_runtime.h>

#define INF_BITS 0x7F800000u
#define AS1 __attribute__((address_space(1)))
#define AS3 __attribute__((address_space(3)))

typedef float f32x4 __attribute__((ext_vector_type(4)));
typedef int i32x4 __attribute__((ext_vector_type(4)));
typedef int i32x8 __attribute__((ext_vector_type(8)));
typedef unsigned int u32x2 __attribute__((ext_vector_type(2)));
typedef unsigned int u32x4 __attribute__((ext_vector_type(4)));

template <int SEL>
static __device__ __forceinline__ float dq8(unsigned int w) {
  return __builtin_amdgcn_cvt_f32_fp8((int)w, SEL);
}

// ---- protos (2000x2048 f32) -> pTf (2048x2048 fp8 e4m3, pad zero) + p2 ----
// p2 computed from the QUANTIZED values (so d^2 = ||xq-pq||^2 exactly).
// also initializes out's min-distance region to +inf.
__global__ __launch_bounds__(256) void k_prep_p(const float* __restrict__ protos,
                                                unsigned char* __restrict__ pTf,
                                                float* __restrict__ p2,
                                                unsigned int* __restrict__ outu) {
  const int row = blockIdx.x;   // 2048
  const int tid = threadIdx.x;  // 256
  const int gi = row * 256 + tid;
  if (gi < 64000) outu[6400 + gi] = INF_BITS;
  __shared__ float red[4];
  float s = 0.f;
  unsigned int w0 = 0u, w1 = 0u;
  if (row < 2000) {
    const float* src = protos + (size_t)row * 2048 + tid * 8;
    f32x4 a = *(const f32x4*)src;
    f32x4 c = *(const f32x4*)(src + 4);
    w0 = (unsigned int)__builtin_amdgcn_cvt_pk_fp8_f32(a.x, a.y, 0, false);
    w0 = (unsigned int)__builtin_amdgcn_cvt_pk_fp8_f32(a.z, a.w, (int)w0, true);
    w1 = (unsigned int)__builtin_amdgcn_cvt_pk_fp8_f32(c.x, c.y, 0, false);
    w1 = (unsigned int)__builtin_amdgcn_cvt_pk_fp8_f32(c.z, c.w, (int)w1, true);
    float q;
    q = dq8<0>(w0); s += q * q;
    q = dq8<1>(w0); s += q * q;
    q = dq8<2>(w0); s += q * q;
    q = dq8<3>(w0); s += q * q;
    q = dq8<0>(w1); s += q * q;
    q = dq8<1>(w1); s += q * q;
    q = dq8<2>(w1); s += q * q;
    q = dq8<3>(w1); s += q * q;
  }
  *(u32x2*)(pTf + (size_t)row * 2048 + tid * 8) = (u32x2){w0, w1};
  #pragma unroll
  for (int off = 32; off; off >>= 1) s += __shfl_xor(s, off);
  if ((tid & 63) == 0) red[tid >> 6] = s;
  __syncthreads();
  if (tid == 0) p2[row] = red[0] + red[1] + red[2] + red[3];
}

// ---- x (b,k,n) f32 -> xTf[(b*196+n)*2048+k] fp8 + x2 partials (quantized) ----
__global__ __launch_bounds__(256) void k_prep_x(const float* __restrict__ x,
                                                unsigned char* __restrict__ xTf,
                                                float* __restrict__ x2p,
                                                float* __restrict__ x2) {
  const int kt = blockIdx.x;  // 32 (64-k chunks of source)
  const int b  = blockIdx.y;  // 33: b==32 -> padding work
  const int tid = threadIdx.x;
  if (b == 32) {
    u32x4* pad = (u32x4*)(xTf + (size_t)6272 * 2048);
    #pragma unroll
    for (int j = tid; j < 512; j += 256)
      pad[kt * 512 + j] = (u32x4){0u, 0u, 0u, 0u};
    if (kt == 0 && tid < 128) x2[6272 + tid] = __uint_as_float(INF_BITS);
    return;
  }
  __shared__ unsigned char Ls[64][208];  // fp8 bytes; stride 208 (4B-aligned)
  const float* src = x + ((size_t)b * 2048 + (size_t)kt * 64) * 196;
  for (int idx = tid; idx < 3136; idx += 256) {
    const int kk = idx / 49, c4 = idx - kk * 49;
    f32x4 v = *(const f32x4*)(src + (size_t)kk * 196 + c4 * 4);
    unsigned int w = (unsigned int)__builtin_amdgcn_cvt_pk_fp8_f32(v.x, v.y, 0, false);
    w = (unsigned int)__builtin_amdgcn_cvt_pk_fp8_f32(v.z, v.w, (int)w, true);
    *(unsigned int*)&Ls[kk][c4 * 4] = w;
  }
  __syncthreads();
  if (tid < 196) {  // x2 partial from quantized values (column tid)
    float s = 0.f;
    #pragma unroll
    for (int j = 0; j < 64; ++j) {
      float v = dq8<0>((unsigned int)Ls[j][tid]);
      s += v * v;
    }
    x2p[kt * 6272 + b * 196 + tid] = s;
  }
  // transposed write-out: per n, 4 x u32x4 (16B) covering this kt's 64 k
  unsigned char* dstb = xTf + (size_t)b * 196 * 2048 + kt * 64;
  for (int idx = tid; idx < 784; idx += 256) {
    const int n = idx >> 2, q = idx & 3;
    const int k0 = q * 16;
    u32x4 v;
    #pragma unroll
    for (int j = 0; j < 4; ++j) {
      v[j] = (unsigned int)Ls[k0 + 4 * j + 0][n] |
             ((unsigned int)Ls[k0 + 4 * j + 1][n] << 8) |
             ((unsigned int)Ls[k0 + 4 * j + 2][n] << 16) |
             ((unsigned int)Ls[k0 + 4 * j + 3][n] << 24);
    }
    *(u32x4*)(dstb + (size_t)n * 2048 + k0) = v;
  }
}

__global__ void k_x2r(const float* __restrict__ x2p, float* __restrict__ x2) {
  int i = blockIdx.x * blockDim.x + threadIdx.x;
  if (i >= 6272) return;
  float s = 0.f;
  #pragma unroll
  for (int c = 0; c < 32; ++c) s += x2p[c * 6272 + i];
  x2[i] = s;
}

// ---- main GEMM: MX-scaled fp8 (mfma_scale 16x16x128, unit E8M0 scales),
// 256x256 tile, BK=128, 8 waves, 2 phases/K-tile, b128 conflict-free reads ----
__global__ __launch_bounds__(512, 2) void k_main(
    const unsigned char* __restrict__ pTf, const unsigned char* __restrict__ xTf,
    const float* __restrict__ p2, const float* __restrict__ x2,
    unsigned int* __restrict__ outu) {
  const int orig = blockIdx.x;
  const int wgid = (orig & 7) * 25 + (orig >> 3);
  const int ptpair = wgid / 50;
  const int rem = wgid - ptpair * 50;
  const int ptile = ptpair * 2 + (rem & 1);  // 0..7
  const int mtile = rem >> 1;                // 0..24
  const int p0 = ptile * 256;
  const int m0 = mtile * 256;
  const int tid = threadIdx.x;
  const int lane = tid & 63;
  const int w = tid >> 6;   // 8 waves
  const int wp = w >> 2;    // A half (128 rows)
  const int wn = w & 3;     // B quarter (64 rows)
  const int lr = lane & 15;
  const int lg = lane >> 4;

  __shared__ __align__(16) char S[131072];  // A[2]:0..64K, B[2]:64K..128K

  f32x4 acc[8][4];
  #pragma unroll
  for (int mi = 0; mi < 8; ++mi)
    #pragma unroll
    for (int ni = 0; ni < 4; ++ni)
      acc[mi][ni] = (f32x4){0.f, 0.f, 0.f, 0.f};

  const int rowbase = tid >> 3;                       // 0..63
  const int chunk = (tid & 7) ^ (rowbase & 7);        // involution
  const char* gA = (const char*)pTf + (size_t)(p0 + rowbase) * 2048 + chunk * 16;
  const char* gB = (const char*)xTf + (size_t)(m0 + rowbase) * 2048 + chunk * 16;
  const int wbase = w * 1024;

#define STAGE_A(c_, kt_, h_) do {                                              \
    const char* s_ = gA + (size_t)((h_) * 128 * 2048) + (size_t)(kt_) * 128;   \
    _Pragma("unroll")                                                          \
    for (int j_ = 0; j_ < 2; ++j_)                                             \
      __builtin_amdgcn_global_load_lds(                                        \
          (const AS1 void*)(s_ + (size_t)j_ * 64 * 2048),                      \
          (AS3 void*)(S + (c_) * 32768 + (h_) * 16384 + j_ * 8192 + wbase),    \
          16, 0, 0);                                                           \
  } while (0)
#define STAGE_B(c_, kt_, h_) do {                                              \
    const char* s_ = gB + (size_t)((h_) * 128 * 2048) + (size_t)(kt_) * 128;   \
    _Pragma("unroll")                                                          \
    for (int j_ = 0; j_ < 2; ++j_)                                             \
      __builtin_amdgcn_global_load_lds(                                        \
          (const AS1 void*)(s_ + (size_t)j_ * 64 * 2048),                      \
          (AS3 void*)(S + 65536 + (c_) * 32768 + (h_) * 16384 + j_ * 8192 + wbase), \
          16, 0, 0);                                                           \
  } while (0)

  // fragment reads: 32B/lane = two b128 at (lg*32)^swz and ^16 — same chunk-XOR
  // pattern as the 0-conflict bf16 kernel. Rows step by 16 so row&7 == lr&7.
  const int swz = ((lr & 7) << 4);
  const int koffA = (lg * 32) ^ swz;
  const int arow = (wp * 128 + lr) * 128;   // + m16*2048 within A region
  const int brow = (wn * 64 + lr) * 128;    // + ni*2048 (B region +65536)

#define READ_A4(dst_, c_, hf_)                                                 \
    _Pragma("unroll")                                                          \
    for (int mi_ = 0; mi_ < 4; ++mi_) {                                        \
      const char* p_ = S + (c_) * 32768 + arow + ((hf_) * 4 + mi_) * 2048;     \
      u32x4 lo_ = *(const u32x4*)(p_ + koffA);                                 \
      u32x4 hi_ = *(const u32x4*)(p_ + (koffA ^ 16));                          \
      dst_[mi_] = __builtin_bit_cast(i32x8,                                    \
          __builtin_shufflevector(lo_, hi_, 0, 1, 2, 3, 4, 5, 6, 7));          \
    }
#define READ_B4(dst_, c_)                                                      \
    _Pragma("unroll")                                                          \
    for (int ni_ = 0; ni_ < 4; ++ni_) {                                        \
      const char* p_ = S + 65536 + (c_) * 32768 + brow + ni_ * 2048;           \
      u32x4 lo_ = *(const u32x4*)(p_ + koffA);                                 \
      u32x4 hi_ = *(const u32x4*)(p_ + (koffA ^ 16));                          \
      dst_[ni_] = __builtin_bit_cast(i32x8,                                    \
          __builtin_shufflevector(lo_, hi_, 0, 1, 2, 3, 4, 5, 6, 7));          \
    }

#define PH_BAR() do { __builtin_amdgcn_sched_barrier(0);                       \
    __builtin_amdgcn_s_barrier(); __builtin_amdgcn_sched_barrier(0); } while (0)
#define LGKM0() do { asm volatile("s_waitcnt lgkmcnt(0)" ::: "memory");        \
    __builtin_amdgcn_sched_barrier(0); } while (0)
// unit scales: E8M0 127 = 2^0; packed 0x7F7F7F7F, opsel 0
#define MFMA_Q(mlo_, af_, bf_) do { __builtin_amdgcn_s_setprio(1);             \
    _Pragma("unroll")                                                          \
    for (int mi_ = 0; mi_ < 4; ++mi_)                                          \
      _Pragma("unroll")                                                        \
      for (int ni_ = 0; ni_ < 4; ++ni_)                                        \
        acc[(mlo_) + mi_][ni_] =                                               \
            __builtin_amdgcn_mfma_scale_f32_16x16x128_f8f6f4(                  \
                af_[mi_], bf_[ni_], acc[(mlo_) + mi_][ni_],                    \
                0, 0, 0, 0x7F7F7F7F, 0, 0x7F7F7F7F);                           \
    __builtin_amdgcn_s_setprio(0); } while (0)

  // Per K-tile (128 k, buf c), 2 phases:
  //  Ph0: read B(8 b128)+A0-3(8); stage A[kt+1]->c^1; bar; lgkm0; 16 MFMA; bar
  //  Ph1: read A4-7(8); stage B[kt+2]->c (B[c] readers passed Ph0 bar);
  //       bar; lgkm0; 16 MFMA; vmcnt(4) retires {B[kt+1],A[kt+1]}; bar
#define KT_BODY(kt_, c_, sa_, sb_, vm_) do {                                   \
    i32x8 af[4], bf[4];                                                        \
    READ_B4(bf, c_);                                                           \
    READ_A4(af, c_, 0);                                                        \
    if (sa_) { STAGE_A((c_) ^ 1, (kt_) + 1, 0); STAGE_A((c_) ^ 1, (kt_) + 1, 1); } \
    PH_BAR(); LGKM0();                                                         \
    MFMA_Q(0, af, bf);                                                         \
    PH_BAR();                                                                  \
    READ_A4(af, c_, 1);                                                        \
    if (sb_) { STAGE_B(c_, (kt_) + 2, 0); STAGE_B(c_, (kt_) + 2, 1); }         \
    PH_BAR(); LGKM0();                                                         \
    MFMA_Q(4, af, bf);                                                         \
    if ((vm_) == 4)      asm volatile("s_waitcnt vmcnt(4)" ::: "memory");      \
    else if ((vm_) == 0) asm volatile("s_waitcnt vmcnt(0)" ::: "memory");      \
    __builtin_amdgcn_sched_barrier(0);                                         \
    PH_BAR();                                                                  \
  } while (0)

  // prologue: A0,B0 -> buf0 ; B1 -> buf1 ; retire {A0,B0}, keep B1 in flight
  STAGE_A(0, 0, 0); STAGE_A(0, 0, 1);
  STAGE_B(0, 0, 0); STAGE_B(0, 0, 1);
  STAGE_B(1, 1, 0); STAGE_B(1, 1, 1);
  asm volatile("s_waitcnt vmcnt(4)" ::: "memory");
  __builtin_amdgcn_sched_barrier(0);
  __builtin_amdgcn_s_barrier();
  __builtin_amdgcn_sched_barrier(0);

  #pragma unroll 1
  for (int it = 0; it < 7; ++it) {
    KT_BODY(2 * it, 0, 1, 1, 4);
    KT_BODY(2 * it + 1, 1, 1, 1, 4);
  }
  KT_BODY(14, 0, 1, 0, 0);   // stages A[15]; no B[16]; drain all
  KT_BODY(15, 1, 0, 0, -1);  // pure compute
#undef KT_BODY
#undef MFMA_Q
#undef READ_A4
#undef READ_B4
#undef STAGE_A
#undef STAGE_B

  // epilogue: d2 = x2[m] + p2[p] - 2*dot ; per-wave 64-col window, <=2 batches
  const int wm_base = m0 + wn * 64;
  const int b_lo = wm_base / 196;
  int b_hi = (wm_base + 63) / 196;
  if (b_hi > 31) b_hi = 31;
  const bool wave_ok = (b_lo < 32);
  float x2v[4];
  int seg0[4];
  #pragma unroll
  for (int ni = 0; ni < 4; ++ni) {
    const int m = wm_base + ni * 16 + lr;  // D col = lane&15
    x2v[ni] = x2[m];
    seg0[ni] = ((m / 196) == b_lo);
  }
  const float INF = __uint_as_float(INF_BITS);
  #pragma unroll
  for (int mi = 0; mi < 8; ++mi) {
    const int prow = p0 + wp * 128 + mi * 16 + 4 * lg;  // D row = 4*(lane>>4)+j
    #pragma unroll
    for (int j = 0; j < 4; ++j) {
      const int p = prow + j;
      const float pp = p2[p];
      float ma = INF, mb = INF;
      #pragma unroll
      for (int ni = 0; ni < 4; ++ni) {
        const float d2 = x2v[ni] + pp - 2.f * acc[mi][ni][j];
        ma = fminf(ma, seg0[ni] ? d2 : INF);
        mb = fminf(mb, seg0[ni] ? INF : d2);
      }
      #pragma unroll
      for (int off = 1; off < 16; off <<= 1) {
        ma = fminf(ma, __shfl_xor(ma, off));
        mb = fminf(mb, __shfl_xor(mb, off));
      }
      if (lr == 0 && p < 2000 && wave_ok) {
        atomicMin(&outu[6400 + b_lo * 2000 + p], __float_as_uint(fmaxf(ma, 0.f)));
        if (b_hi != b_lo)
          atomicMin(&outu[6400 + b_hi * 2000 + p], __float_as_uint(fmaxf(mb, 0.f)));
      }
    }
  }
}

// ---- post: d = sqrt(max(d2,1e-12)) in place; sim -> simbuf ----
__global__ void k_post(float* __restrict__ out, float* __restrict__ simbuf) {
  int i = blockIdx.x * blockDim.x + threadIdx.x;
  if (i >= 64000) return;
  float d2 = out[6400 + i];
  float d = sqrtf(fmaxf(d2, 1e-12f));
  out[6400 + i] = d;
  simbuf[i] = logf((d + 1.0f) / (d + 1e-7f));
}

// ---- scores: one wave per (b, class) pair ----
__global__ __launch_bounds__(256) void k_scores(const float* __restrict__ fc_w,
                                                const float* __restrict__ simbuf,
                                                float* __restrict__ out) {
  const int id = blockIdx.x * 4 + (threadIdx.x >> 6);  // 0..6399
  const int lane = threadIdx.x & 63;
  const int b = id / 200;
  const int c = id - b * 200;
  const f32x4* sv = (const f32x4*)(simbuf + (size_t)b * 2000);
  const f32x4* wv = (const f32x4*)(fc_w + (size_t)c * 2000);
  float s = 0.f;
  #pragma unroll
  for (int it = 0; it < 8; ++it) {
    int i = lane + it * 64;
    if (i < 500) {
      f32x4 a = sv[i], w4 = wv[i];
      s += a.x * w4.x + a.y * w4.y + a.z * w4.z + a.w * w4.w;
    }
  }
  #pragma unroll
  for (int off = 32; off; off >>= 1) s += __shfl_xor(s, off);
  if (lane == 0) out[b * 200 + c] = s;
}

extern "C" void kernel_launch(void* const* d_in, const int* in_sizes, int n_in,
                              void* d_out, int out_size, void* d_ws, size_t ws_size,
                              hipStream_t stream) {
  const float* x      = (const float*)d_in[0];  // (32, 2048, 14, 14) f32
  const float* protos = (const float*)d_in[1];  // (1, 2000, 2048) f32
  const float* fc_w   = (const float*)d_in[2];  // (200, 2000) f32
  float* out = (float*)d_out;                   // 6400 scores + 64000 min-dists

  char* wsb = (char*)d_ws;
  unsigned char* pTf = (unsigned char*)wsb;               // 2048*2048 = 4194304
  unsigned char* xTf = (unsigned char*)(wsb + 4194304);   // 6400*2048 = 13107200
  float* p2   = (float*)(wsb + 17301504);                 // 2048 f32
  float* x2   = (float*)(wsb + 17309696);                 // 6400 f32 (pad +inf)
  float* x2p  = (float*)(wsb + 17335296);                 // 32*6272 f32
  float* simb = (float*)(wsb + 17335296);                 // aliases x2p (dead after k_x2r)

  k_prep_p<<<2048, 256, 0, stream>>>(protos, pTf, p2, (unsigned int*)d_out);
  k_prep_x<<<dim3(32, 33), 256, 0, stream>>>(x, xTf, x2p, x2);
  k_x2r<<<25, 256, 0, stream>>>(x2p, x2);
  k_main<<<200, 512, 0, stream>>>(pTf, xTf, p2, x2, (unsigned int*)d_out);
  k_post<<<250, 256, 0, stream>>>(out, simb);
  k_scores<<<1600, 256, 0, stream>>>(fc_w, simb, out);
}

// Round 17
// 83.557 us; speedup vs baseline: 1.9040x; 1.0474x over previous
//
#include <hip/hip_runtime.h>

#define INF_BITS 0x7F800000u
#define AS1 __attribute__((address_space(1)))
#define AS3 __attribute__((address_space(3)))

typedef float f32x4 __attribute__((ext_vector_type(4)));
typedef int i32x4 __attribute__((ext_vector_type(4)));
typedef int i32x8 __attribute__((ext_vector_type(8)));
typedef unsigned int u32x2 __attribute__((ext_vector_type(2)));
typedef unsigned int u32x4 __attribute__((ext_vector_type(4)));

template <int SEL>
static __device__ __forceinline__ float dq8(unsigned int w) {
  return __builtin_amdgcn_cvt_f32_fp8((int)w, SEL);
}

// ---- protos (2000x2048 f32) -> pTf (2048x2048 fp8 e4m3, pad zero) + p2 ----
// p2 computed from the QUANTIZED values (so d^2 = ||xq-pq||^2 exactly).
// also initializes out's min-distance region to +inf.
__global__ __launch_bounds__(256) void k_prep_p(const float* __restrict__ protos,
                                                unsigned char* __restrict__ pTf,
                                                float* __restrict__ p2,
                                                unsigned int* __restrict__ outu) {
  const int row = blockIdx.x;   // 2048
  const int tid = threadIdx.x;  // 256
  const int gi = row * 256 + tid;
  if (gi < 64000) outu[6400 + gi] = INF_BITS;
  __shared__ float red[4];
  float s = 0.f;
  unsigned int w0 = 0u, w1 = 0u;
  if (row < 2000) {
    const float* src = protos + (size_t)row * 2048 + tid * 8;
    f32x4 a = *(const f32x4*)src;
    f32x4 c = *(const f32x4*)(src + 4);
    w0 = (unsigned int)__builtin_amdgcn_cvt_pk_fp8_f32(a.x, a.y, 0, false);
    w0 = (unsigned int)__builtin_amdgcn_cvt_pk_fp8_f32(a.z, a.w, (int)w0, true);
    w1 = (unsigned int)__builtin_amdgcn_cvt_pk_fp8_f32(c.x, c.y, 0, false);
    w1 = (unsigned int)__builtin_amdgcn_cvt_pk_fp8_f32(c.z, c.w, (int)w1, true);
    float q;
    q = dq8<0>(w0); s += q * q;
    q = dq8<1>(w0); s += q * q;
    q = dq8<2>(w0); s += q * q;
    q = dq8<3>(w0); s += q * q;
    q = dq8<0>(w1); s += q * q;
    q = dq8<1>(w1); s += q * q;
    q = dq8<2>(w1); s += q * q;
    q = dq8<3>(w1); s += q * q;
  }
  *(u32x2*)(pTf + (size_t)row * 2048 + tid * 8) = (u32x2){w0, w1};
  #pragma unroll
  for (int off = 32; off; off >>= 1) s += __shfl_xor(s, off);
  if ((tid & 63) == 0) red[tid >> 6] = s;
  __syncthreads();
  if (tid == 0) p2[row] = red[0] + red[1] + red[2] + red[3];
}

// ---- x (b,k,n) f32 -> xTf[(b*196+n)*2048+k] fp8 + x2 partials (quantized) ----
__global__ __launch_bounds__(256) void k_prep_x(const float* __restrict__ x,
                                                unsigned char* __restrict__ xTf,
                                                float* __restrict__ x2p,
                                                float* __restrict__ x2) {
  const int kt = blockIdx.x;  // 32 (64-k chunks of source)
  const int b  = blockIdx.y;  // 33: b==32 -> padding work
  const int tid = threadIdx.x;
  if (b == 32) {
    u32x4* pad = (u32x4*)(xTf + (size_t)6272 * 2048);
    #pragma unroll
    for (int j = tid; j < 512; j += 256)
      pad[kt * 512 + j] = (u32x4){0u, 0u, 0u, 0u};
    if (kt == 0 && tid < 128) x2[6272 + tid] = __uint_as_float(INF_BITS);
    return;
  }
  __shared__ unsigned char Ls[64][208];  // fp8 bytes; stride 208 (4B-aligned)
  const float* src = x + ((size_t)b * 2048 + (size_t)kt * 64) * 196;
  for (int idx = tid; idx < 3136; idx += 256) {
    const int kk = idx / 49, c4 = idx - kk * 49;
    f32x4 v = *(const f32x4*)(src + (size_t)kk * 196 + c4 * 4);
    unsigned int w = (unsigned int)__builtin_amdgcn_cvt_pk_fp8_f32(v.x, v.y, 0, false);
    w = (unsigned int)__builtin_amdgcn_cvt_pk_fp8_f32(v.z, v.w, (int)w, true);
    *(unsigned int*)&Ls[kk][c4 * 4] = w;
  }
  __syncthreads();
  if (tid < 196) {  // x2 partial from quantized values (column tid)
    float s = 0.f;
    #pragma unroll
    for (int j = 0; j < 64; ++j) {
      float v = dq8<0>((unsigned int)Ls[j][tid]);
      s += v * v;
    }
    x2p[kt * 6272 + b * 196 + tid] = s;
  }
  // transposed write-out: per n, 4 x u32x4 (16B) covering this kt's 64 k
  unsigned char* dstb = xTf + (size_t)b * 196 * 2048 + kt * 64;
  for (int idx = tid; idx < 784; idx += 256) {
    const int n = idx >> 2, q = idx & 3;
    const int k0 = q * 16;
    u32x4 v;
    #pragma unroll
    for (int j = 0; j < 4; ++j) {
      v[j] = (unsigned int)Ls[k0 + 4 * j + 0][n] |
             ((unsigned int)Ls[k0 + 4 * j + 1][n] << 8) |
             ((unsigned int)Ls[k0 + 4 * j + 2][n] << 16) |
             ((unsigned int)Ls[k0 + 4 * j + 3][n] << 24);
    }
    *(u32x4*)(dstb + (size_t)n * 2048 + k0) = v;
  }
}

__global__ void k_x2r(const float* __restrict__ x2p, float* __restrict__ x2) {
  int i = blockIdx.x * blockDim.x + threadIdx.x;
  if (i >= 6272) return;
  float s = 0.f;
  #pragma unroll
  for (int c = 0; c < 32; ++c) s += x2p[c * 6272 + i];
  x2[i] = s;
}

// ---- main GEMM: MX-scaled fp8 (mfma_scale 16x16x128, unit E8M0 scales),
// 256x256 tile, BK=128, 8 waves. Low-pressure interior (A-frag ping-pong,
// <=48 frag regs) + r15's PROVEN vmcnt(4) ledger: at end of tile kt the
// outstanding order is B[kt+1](4), A[kt+1](4), B[kt+2](4); vmcnt(4) retires
// exactly {B[kt+1], A[kt+1]}. (r16's vmcnt(8) left A[kt+1] flying -> race.)
__global__ __launch_bounds__(512, 2) void k_main(
    const unsigned char* __restrict__ pTf, const unsigned char* __restrict__ xTf,
    const float* __restrict__ p2, const float* __restrict__ x2,
    unsigned int* __restrict__ outu) {
  const int orig = blockIdx.x;
  const int wgid = (orig & 7) * 25 + (orig >> 3);
  const int ptpair = wgid / 50;
  const int rem = wgid - ptpair * 50;
  const int ptile = ptpair * 2 + (rem & 1);  // 0..7
  const int mtile = rem >> 1;                // 0..24
  const int p0 = ptile * 256;
  const int m0 = mtile * 256;
  const int tid = threadIdx.x;
  const int lane = tid & 63;
  const int w = tid >> 6;   // 8 waves
  const int wp = w >> 2;    // A half (128 rows)
  const int wn = w & 3;     // B quarter (64 rows)
  const int lr = lane & 15;
  const int lg = lane >> 4;

  __shared__ __align__(16) char S[131072];  // A[2]:0..64K, B[2]:64K..128K

  f32x4 acc[8][4];
  #pragma unroll
  for (int mi = 0; mi < 8; ++mi)
    #pragma unroll
    for (int ni = 0; ni < 4; ++ni)
      acc[mi][ni] = (f32x4){0.f, 0.f, 0.f, 0.f};

  const int rowbase = tid >> 3;                       // 0..63
  const int chunk = (tid & 7) ^ (rowbase & 7);        // involution
  const char* gA = (const char*)pTf + (size_t)(p0 + rowbase) * 2048 + chunk * 16;
  const char* gB = (const char*)xTf + (size_t)(m0 + rowbase) * 2048 + chunk * 16;
  const int wbase = w * 1024;

#define STAGE_A(c_, kt_, h_) do {                                              \
    const char* s_ = gA + (size_t)((h_) * 128 * 2048) + (size_t)(kt_) * 128;   \
    _Pragma("unroll")                                                          \
    for (int j_ = 0; j_ < 2; ++j_)                                             \
      __builtin_amdgcn_global_load_lds(                                        \
          (const AS1 void*)(s_ + (size_t)j_ * 64 * 2048),                      \
          (AS3 void*)(S + (c_) * 32768 + (h_) * 16384 + j_ * 8192 + wbase),    \
          16, 0, 0);                                                           \
  } while (0)
#define STAGE_B(c_, kt_, h_) do {                                              \
    const char* s_ = gB + (size_t)((h_) * 128 * 2048) + (size_t)(kt_) * 128;   \
    _Pragma("unroll")                                                          \
    for (int j_ = 0; j_ < 2; ++j_)                                             \
      __builtin_amdgcn_global_load_lds(                                        \
          (const AS1 void*)(s_ + (size_t)j_ * 64 * 2048),                      \
          (AS3 void*)(S + 65536 + (c_) * 32768 + (h_) * 16384 + j_ * 8192 + wbase), \
          16, 0, 0);                                                           \
  } while (0)

  // fragment reads: 32B/lane = two b128 at (lg*32)^swz and ^16 (chunk-XOR).
  const int swz = ((lr & 7) << 4);
  const int koffA = (lg * 32) ^ swz;
  const int arow = (wp * 128 + lr) * 128;   // + a*2048, a = 0..7
  const int brow = (wn * 64 + lr) * 128;    // + ni*2048 (B region +65536)

#define READ_A1(dst_, c_, a_) do {                                             \
    const char* p_ = S + (c_) * 32768 + arow + (a_) * 2048;                    \
    u32x4 lo_ = *(const u32x4*)(p_ + koffA);                                   \
    u32x4 hi_ = *(const u32x4*)(p_ + (koffA ^ 16));                            \
    dst_ = __builtin_bit_cast(i32x8,                                           \
        __builtin_shufflevector(lo_, hi_, 0, 1, 2, 3, 4, 5, 6, 7));            \
  } while (0)
#define READ_B4(dst_, c_)                                                      \
    _Pragma("unroll")                                                          \
    for (int ni_ = 0; ni_ < 4; ++ni_) {                                        \
      const char* p_ = S + 65536 + (c_) * 32768 + brow + ni_ * 2048;           \
      u32x4 lo_ = *(const u32x4*)(p_ + koffA);                                 \
      u32x4 hi_ = *(const u32x4*)(p_ + (koffA ^ 16));                          \
      dst_[ni_] = __builtin_bit_cast(i32x8,                                    \
          __builtin_shufflevector(lo_, hi_, 0, 1, 2, 3, 4, 5, 6, 7));          \
    }

#define SCHED() __builtin_amdgcn_sched_barrier(0)
#define SBAR() do { SCHED(); __builtin_amdgcn_s_barrier(); SCHED(); } while (0)
#define LGKM0() do { asm volatile("s_waitcnt lgkmcnt(0)" ::: "memory"); SCHED(); } while (0)
// unit scales: E8M0 127 = 2^0; packed 0x7F7F7F7F
#define MFMA4(mi_, af_, bf_) do { __builtin_amdgcn_s_setprio(1);               \
    _Pragma("unroll")                                                          \
    for (int ni_ = 0; ni_ < 4; ++ni_)                                          \
      acc[mi_][ni_] = __builtin_amdgcn_mfma_scale_f32_16x16x128_f8f6f4(        \
          af_, bf_[ni_], acc[mi_][ni_], 0, 0, 0, 0x7F7F7F7F, 0, 0x7F7F7F7F);   \
    __builtin_amdgcn_s_setprio(0); } while (0)

  // Per K-tile kt (buf c): stage A[kt+1] at top; interior = READ_B4 then
  // A-frag ping-pong (read frag i+1 || MFMA frag i); release; stage B[kt+2];
  // vmcnt(4) retires {B[kt+1], A[kt+1]}, leaves B[kt+2] in flight.
#define KT_BODY(kt_, c_, sa_, sb_, vm_, tail_) do {                            \
    if (sa_) { STAGE_A((c_) ^ 1, (kt_) + 1, 0); STAGE_A((c_) ^ 1, (kt_) + 1, 1); } \
    i32x8 bf[4], af0, af1;                                                     \
    READ_B4(bf, c_);                                                           \
    READ_A1(af0, c_, 0);                                                       \
    READ_A1(af1, c_, 1); MFMA4(0, af0, bf); SCHED();                           \
    READ_A1(af0, c_, 2); MFMA4(1, af1, bf); SCHED();                           \
    READ_A1(af1, c_, 3); MFMA4(2, af0, bf); SCHED();                           \
    READ_A1(af0, c_, 4); MFMA4(3, af1, bf); SCHED();                           \
    READ_A1(af1, c_, 5); MFMA4(4, af0, bf); SCHED();                           \
    READ_A1(af0, c_, 6); MFMA4(5, af1, bf); SCHED();                           \
    READ_A1(af1, c_, 7); MFMA4(6, af0, bf); SCHED();                           \
    MFMA4(7, af1, bf);                                                         \
    if (!(tail_)) {                                                            \
      LGKM0();                                                                 \
      SBAR();  /* release buf c */                                             \
      if (sb_) { STAGE_B(c_, (kt_) + 2, 0); STAGE_B(c_, (kt_) + 2, 1); }       \
      if ((vm_) == 4)      asm volatile("s_waitcnt vmcnt(4)" ::: "memory");    \
      else if ((vm_) == 0) asm volatile("s_waitcnt vmcnt(0)" ::: "memory");    \
      SCHED();                                                                 \
      SBAR();  /* arrival buf c^1 */                                           \
    }                                                                          \
  } while (0)

  // prologue: A[0],B[0] -> buf0 ; B[1] -> buf1 (12 loads); vmcnt(4) retires
  // {A[0], B[0]}, keeps B[1] in flight.
  STAGE_A(0, 0, 0); STAGE_A(0, 0, 1);
  STAGE_B(0, 0, 0); STAGE_B(0, 0, 1);
  STAGE_B(1, 1, 0); STAGE_B(1, 1, 1);
  asm volatile("s_waitcnt vmcnt(4)" ::: "memory");
  SCHED();
  __builtin_amdgcn_s_barrier();
  SCHED();

  #pragma unroll 1
  for (int it = 0; it < 7; ++it) {
    KT_BODY(2 * it, 0, 1, 1, 4, 0);
    KT_BODY(2 * it + 1, 1, 1, 1, 4, 0);
  }
  KT_BODY(14, 0, 1, 0, 0, 0);   // stages A[15]; no B[16]; vmcnt(0) drains all
  KT_BODY(15, 1, 0, 0, -1, 1);  // pure compute
#undef KT_BODY
#undef MFMA4
#undef READ_A1
#undef READ_B4
#undef STAGE_A
#undef STAGE_B

  // epilogue: d2 = x2[m] + p2[p] - 2*dot ; per-wave 64-col window, <=2 batches
  const int wm_base = m0 + wn * 64;
  const int b_lo = wm_base / 196;
  int b_hi = (wm_base + 63) / 196;
  if (b_hi > 31) b_hi = 31;
  const bool wave_ok = (b_lo < 32);
  float x2v[4];
  int seg0[4];
  #pragma unroll
  for (int ni = 0; ni < 4; ++ni) {
    const int m = wm_base + ni * 16 + lr;  // D col = lane&15
    x2v[ni] = x2[m];
    seg0[ni] = ((m / 196) == b_lo);
  }
  const float INF = __uint_as_float(INF_BITS);
  #pragma unroll
  for (int mi = 0; mi < 8; ++mi) {
    const int prow = p0 + wp * 128 + mi * 16 + 4 * lg;  // D row = 4*(lane>>4)+j
    #pragma unroll
    for (int j = 0; j < 4; ++j) {
      const int p = prow + j;
      const float pp = p2[p];
      float ma = INF, mb = INF;
      #pragma unroll
      for (int ni = 0; ni < 4; ++ni) {
        const float d2 = x2v[ni] + pp - 2.f * acc[mi][ni][j];
        ma = fminf(ma, seg0[ni] ? d2 : INF);
        mb = fminf(mb, seg0[ni] ? INF : d2);
      }
      #pragma unroll
      for (int off = 1; off < 16; off <<= 1) {
        ma = fminf(ma, __shfl_xor(ma, off));
        mb = fminf(mb, __shfl_xor(mb, off));
      }
      if (lr == 0 && p < 2000 && wave_ok) {
        atomicMin(&outu[6400 + b_lo * 2000 + p], __float_as_uint(fmaxf(ma, 0.f)));
        if (b_hi != b_lo)
          atomicMin(&outu[6400 + b_hi * 2000 + p], __float_as_uint(fmaxf(mb, 0.f)));
      }
    }
  }
}

// ---- post: d = sqrt(max(d2,1e-12)) in place; sim -> simbuf ----
__global__ void k_post(float* __restrict__ out, float* __restrict__ simbuf) {
  int i = blockIdx.x * blockDim.x + threadIdx.x;
  if (i >= 64000) return;
  float d2 = out[6400 + i];
  float d = sqrtf(fmaxf(d2, 1e-12f));
  out[6400 + i] = d;
  simbuf[i] = logf((d + 1.0f) / (d + 1e-7f));
}

// ---- scores: one wave per (b, class) pair ----
__global__ __launch_bounds__(256) void k_scores(const float* __restrict__ fc_w,
                                                const float* __restrict__ simbuf,
                                                float* __restrict__ out) {
  const int id = blockIdx.x * 4 + (threadIdx.x >> 6);  // 0..6399
  const int lane = threadIdx.x & 63;
  const int b = id / 200;
  const int c = id - b * 200;
  const f32x4* sv = (const f32x4*)(simbuf + (size_t)b * 2000);
  const f32x4* wv = (const f32x4*)(fc_w + (size_t)c * 2000);
  float s = 0.f;
  #pragma unroll
  for (int it = 0; it < 8; ++it) {
    int i = lane + it * 64;
    if (i < 500) {
      f32x4 a = sv[i], w4 = wv[i];
      s += a.x * w4.x + a.y * w4.y + a.z * w4.z + a.w * w4.w;
    }
  }
  #pragma unroll
  for (int off = 32; off; off >>= 1) s += __shfl_xor(s, off);
  if (lane == 0) out[b * 200 + c] = s;
}

extern "C" void kernel_launch(void* const* d_in, const int* in_sizes, int n_in,
                              void* d_out, int out_size, void* d_ws, size_t ws_size,
                              hipStream_t stream) {
  const float* x      = (const float*)d_in[0];  // (32, 2048, 14, 14) f32
  const float* protos = (const float*)d_in[1];  // (1, 2000, 2048) f32
  const float* fc_w   = (const float*)d_in[2];  // (200, 2000) f32
  float* out = (float*)d_out;                   // 6400 scores + 64000 min-dists

  char* wsb = (char*)d_ws;
  unsigned char* pTf = (unsigned char*)wsb;               // 2048*2048 = 4194304
  unsigned char* xTf = (unsigned char*)(wsb + 4194304);   // 6400*2048 = 13107200
  float* p2   = (float*)(wsb + 17301504);                 // 2048 f32
  float* x2   = (float*)(wsb + 17309696);                 // 6400 f32 (pad +inf)
  float* x2p  = (float*)(wsb + 17335296);                 // 32*6272 f32
  float* simb = (float*)(wsb + 17335296);                 // aliases x2p (dead after k_x2r)

  k_prep_p<<<2048, 256, 0, stream>>>(protos, pTf, p2, (unsigned int*)d_out);
  k_prep_x<<<dim3(32, 33), 256, 0, stream>>>(x, xTf, x2p, x2);
  k_x2r<<<25, 256, 0, stream>>>(x2p, x2);
  k_main<<<200, 512, 0, stream>>>(pTf, xTf, p2, x2, (unsigned int*)d_out);
  k_post<<<250, 256, 0, stream>>>(out, simb);
  k_scores<<<1600, 256, 0, stream>>>(fc_w, simb, out);
}

// Round 18
// 83.162 us; speedup vs baseline: 1.9131x; 1.0047x over previous
//
#include <hip/hip_runtime.h>

#define INF_BITS 0x7F800000u
#define AS1 __attribute__((address_space(1)))
#define AS3 __attribute__((address_space(3)))

typedef float f32x4 __attribute__((ext_vector_type(4)));
typedef int i32x8 __attribute__((ext_vector_type(8)));
typedef unsigned int u32x2 __attribute__((ext_vector_type(2)));
typedef unsigned int u32x4 __attribute__((ext_vector_type(4)));

template <int SEL>
static __device__ __forceinline__ float dq8(unsigned int w) {
  return __builtin_amdgcn_cvt_f32_fp8((int)w, SEL);
}

// ---- protos (2000x2048 f32) -> pTf (2048x2048 fp8 e4m3, pad zero) + p2 ----
__global__ __launch_bounds__(256) void k_prep_p(const float* __restrict__ protos,
                                                unsigned char* __restrict__ pTf,
                                                float* __restrict__ p2,
                                                unsigned int* __restrict__ outu) {
  const int row = blockIdx.x;   // 2048
  const int tid = threadIdx.x;  // 256
  const int gi = row * 256 + tid;
  if (gi < 64000) outu[6400 + gi] = INF_BITS;
  __shared__ float red[4];
  float s = 0.f;
  unsigned int w0 = 0u, w1 = 0u;
  if (row < 2000) {
    const float* src = protos + (size_t)row * 2048 + tid * 8;
    f32x4 a = *(const f32x4*)src;
    f32x4 c = *(const f32x4*)(src + 4);
    w0 = (unsigned int)__builtin_amdgcn_cvt_pk_fp8_f32(a.x, a.y, 0, false);
    w0 = (unsigned int)__builtin_amdgcn_cvt_pk_fp8_f32(a.z, a.w, (int)w0, true);
    w1 = (unsigned int)__builtin_amdgcn_cvt_pk_fp8_f32(c.x, c.y, 0, false);
    w1 = (unsigned int)__builtin_amdgcn_cvt_pk_fp8_f32(c.z, c.w, (int)w1, true);
    float q;
    q = dq8<0>(w0); s += q * q;
    q = dq8<1>(w0); s += q * q;
    q = dq8<2>(w0); s += q * q;
    q = dq8<3>(w0); s += q * q;
    q = dq8<0>(w1); s += q * q;
    q = dq8<1>(w1); s += q * q;
    q = dq8<2>(w1); s += q * q;
    q = dq8<3>(w1); s += q * q;
  }
  *(u32x2*)(pTf + (size_t)row * 2048 + tid * 8) = (u32x2){w0, w1};
  #pragma unroll
  for (int off = 32; off; off >>= 1) s += __shfl_xor(s, off);
  if ((tid & 63) == 0) red[tid >> 6] = s;
  __syncthreads();
  if (tid == 0) p2[row] = red[0] + red[1] + red[2] + red[3];
}

// ---- x (b,k,n) f32 -> xTf[(b*196+n)*2048+k] fp8 + x2 partials (quantized) ----
__global__ __launch_bounds__(256) void k_prep_x(const float* __restrict__ x,
                                                unsigned char* __restrict__ xTf,
                                                float* __restrict__ x2p,
                                                float* __restrict__ x2) {
  const int kt = blockIdx.x;  // 32 (64-k chunks of source)
  const int b  = blockIdx.y;  // 33: b==32 -> padding work
  const int tid = threadIdx.x;
  if (b == 32) {
    u32x4* pad = (u32x4*)(xTf + (size_t)6272 * 2048);
    #pragma unroll
    for (int j = tid; j < 512; j += 256)
      pad[kt * 512 + j] = (u32x4){0u, 0u, 0u, 0u};
    if (kt == 0 && tid < 128) x2[6272 + tid] = __uint_as_float(INF_BITS);
    return;
  }
  __shared__ unsigned char Ls[64][208];  // fp8 bytes; stride 208 (4B-aligned)
  const float* src = x + ((size_t)b * 2048 + (size_t)kt * 64) * 196;
  for (int idx = tid; idx < 3136; idx += 256) {
    const int kk = idx / 49, c4 = idx - kk * 49;
    f32x4 v = *(const f32x4*)(src + (size_t)kk * 196 + c4 * 4);
    unsigned int w = (unsigned int)__builtin_amdgcn_cvt_pk_fp8_f32(v.x, v.y, 0, false);
    w = (unsigned int)__builtin_amdgcn_cvt_pk_fp8_f32(v.z, v.w, (int)w, true);
    *(unsigned int*)&Ls[kk][c4 * 4] = w;
  }
  __syncthreads();
  if (tid < 196) {  // x2 partial from quantized values (column tid)
    float s = 0.f;
    #pragma unroll
    for (int j = 0; j < 64; ++j) {
      float v = dq8<0>((unsigned int)Ls[j][tid]);
      s += v * v;
    }
    x2p[kt * 6272 + b * 196 + tid] = s;
  }
  // transposed write-out: per n, 4 x u32x4 (16B) covering this kt's 64 k
  unsigned char* dstb = xTf + (size_t)b * 196 * 2048 + kt * 64;
  for (int idx = tid; idx < 784; idx += 256) {
    const int n = idx >> 2, q = idx & 3;
    const int k0 = q * 16;
    u32x4 v;
    #pragma unroll
    for (int j = 0; j < 4; ++j) {
      v[j] = (unsigned int)Ls[k0 + 4 * j + 0][n] |
             ((unsigned int)Ls[k0 + 4 * j + 1][n] << 8) |
             ((unsigned int)Ls[k0 + 4 * j + 2][n] << 16) |
             ((unsigned int)Ls[k0 + 4 * j + 3][n] << 24);
    }
    *(u32x4*)(dstb + (size_t)n * 2048 + k0) = v;
  }
}

__global__ void k_x2r(const float* __restrict__ x2p, float* __restrict__ x2) {
  int i = blockIdx.x * blockDim.x + threadIdx.x;
  if (i >= 6272) return;
  float s = 0.f;
  #pragma unroll
  for (int c = 0; c < 32; ++c) s += x2p[c * 6272 + i];
  x2[i] = s;
}

// ---- main GEMM: MX-scaled fp8, 256p x 128m tile, BK=128, 8 waves (4p x 2m).
// acc halved to 64 regs/thread -> fits the 256-reg budget, no spill.
// Ledger: A-tile = 4 gload issues, B = 2. End of tile kt outstanding order:
// B[kt+1](2), A[kt+1](4), B[kt+2](2) -> vmcnt(2) retires {B[kt+1], A[kt+1]}.
__global__ __launch_bounds__(512, 2) void k_main(
    const unsigned char* __restrict__ pTf, const unsigned char* __restrict__ xTf,
    const float* __restrict__ p2, const float* __restrict__ x2,
    unsigned int* __restrict__ outu) {
  // 400 = 8 XCD x 50: XCD x owns ptile x (A panel 512 KB, L2-resident)
  const int orig = blockIdx.x;
  const int wgid = (orig & 7) * 50 + (orig >> 3);
  const int ptile = wgid / 50;   // 0..7
  const int mtile = wgid - ptile * 50;  // 0..49
  const int p0 = ptile * 256;
  const int m0 = mtile * 128;
  const int tid = threadIdx.x;
  const int lane = tid & 63;
  const int w = tid >> 6;   // 8 waves
  const int wp = w >> 1;    // A quarter (64 rows)
  const int wn = w & 1;     // B half (64 rows)
  const int lr = lane & 15;
  const int lg = lane >> 4;

  __shared__ __align__(16) char S[98304];  // A[2]: 0/32768 (32K), B[2]: 65536+c*16384

  f32x4 acc[4][4];
  #pragma unroll
  for (int mi = 0; mi < 4; ++mi)
    #pragma unroll
    for (int ni = 0; ni < 4; ++ni)
      acc[mi][ni] = (f32x4){0.f, 0.f, 0.f, 0.f};

  const int rowbase = tid >> 3;                       // 0..63
  const int chunk = (tid & 7) ^ (rowbase & 7);        // involution
  const char* gA = (const char*)pTf + (size_t)(p0 + rowbase) * 2048 + chunk * 16;
  const char* gB = (const char*)xTf + (size_t)(m0 + rowbase) * 2048 + chunk * 16;
  const int wbase = w * 1024;

// A tile: 256 rows x 128B = 4 issues of 64 rows (8KB each)
#define STAGE_A(c_, kt_) do {                                                  \
    const char* s_ = gA + (size_t)(kt_) * 128;                                 \
    _Pragma("unroll")                                                          \
    for (int j_ = 0; j_ < 4; ++j_)                                             \
      __builtin_amdgcn_global_load_lds(                                        \
          (const AS1 void*)(s_ + (size_t)j_ * 64 * 2048),                      \
          (AS3 void*)(S + (c_) * 32768 + j_ * 8192 + wbase), 16, 0, 0);        \
  } while (0)
// B tile: 128 rows x 128B = 2 issues
#define STAGE_B(c_, kt_) do {                                                  \
    const char* s_ = gB + (size_t)(kt_) * 128;                                 \
    _Pragma("unroll")                                                          \
    for (int j_ = 0; j_ < 2; ++j_)                                             \
      __builtin_amdgcn_global_load_lds(                                        \
          (const AS1 void*)(s_ + (size_t)j_ * 64 * 2048),                      \
          (AS3 void*)(S + 65536 + (c_) * 16384 + j_ * 8192 + wbase), 16, 0, 0);\
  } while (0)

  // fragment reads: 32B/lane = two b128 at (lg*32)^swz and ^16 (chunk-XOR).
  const int swz = ((lr & 7) << 4);
  const int koffA = (lg * 32) ^ swz;
  const int arow = (wp * 64 + lr) * 128;   // + a*2048, a = 0..3 (16-row steps)
  const int brow = (wn * 64 + lr) * 128;   // + ni*2048 (B region)

#define READ_A1(dst_, c_, a_) do {                                             \
    const char* p_ = S + (c_) * 32768 + arow + (a_) * 2048;                    \
    u32x4 lo_ = *(const u32x4*)(p_ + koffA);                                   \
    u32x4 hi_ = *(const u32x4*)(p_ + (koffA ^ 16));                            \
    dst_ = __builtin_bit_cast(i32x8,                                           \
        __builtin_shufflevector(lo_, hi_, 0, 1, 2, 3, 4, 5, 6, 7));            \
  } while (0)
#define READ_B4(dst_, c_)                                                      \
    _Pragma("unroll")                                                          \
    for (int ni_ = 0; ni_ < 4; ++ni_) {                                        \
      const char* p_ = S + 65536 + (c_) * 16384 + brow + ni_ * 2048;           \
      u32x4 lo_ = *(const u32x4*)(p_ + koffA);                                 \
      u32x4 hi_ = *(const u32x4*)(p_ + (koffA ^ 16));                          \
      dst_[ni_] = __builtin_bit_cast(i32x8,                                    \
          __builtin_shufflevector(lo_, hi_, 0, 1, 2, 3, 4, 5, 6, 7));          \
    }

#define SCHED() __builtin_amdgcn_sched_barrier(0)
#define SBAR() do { SCHED(); __builtin_amdgcn_s_barrier(); SCHED(); } while (0)
#define LGKM0() do { asm volatile("s_waitcnt lgkmcnt(0)" ::: "memory"); SCHED(); } while (0)
// unit scales: E8M0 127 = 2^0; packed 0x7F7F7F7F
#define MFMA4(mi_, af_, bf_) do { __builtin_amdgcn_s_setprio(1);               \
    _Pragma("unroll")                                                          \
    for (int ni_ = 0; ni_ < 4; ++ni_)                                          \
      acc[mi_][ni_] = __builtin_amdgcn_mfma_scale_f32_16x16x128_f8f6f4(        \
          af_, bf_[ni_], acc[mi_][ni_], 0, 0, 0, 0x7F7F7F7F, 0, 0x7F7F7F7F);   \
    __builtin_amdgcn_s_setprio(0); } while (0)

#define KT_BODY(kt_, c_, sa_, sb_, vm_, tail_) do {                            \
    if (sa_) STAGE_A((c_) ^ 1, (kt_) + 1);                                     \
    i32x8 bf[4], af0, af1;                                                     \
    READ_B4(bf, c_);                                                           \
    READ_A1(af0, c_, 0);                                                       \
    READ_A1(af1, c_, 1); MFMA4(0, af0, bf); SCHED();                           \
    READ_A1(af0, c_, 2); MFMA4(1, af1, bf); SCHED();                           \
    READ_A1(af1, c_, 3); MFMA4(2, af0, bf); SCHED();                           \
    MFMA4(3, af1, bf);                                                         \
    if (!(tail_)) {                                                            \
      LGKM0();                                                                 \
      SBAR();  /* release buf c */                                             \
      if (sb_) STAGE_B(c_, (kt_) + 2);                                         \
      if ((vm_) == 2)      asm volatile("s_waitcnt vmcnt(2)" ::: "memory");    \
      else if ((vm_) == 0) asm volatile("s_waitcnt vmcnt(0)" ::: "memory");    \
      SCHED();                                                                 \
      SBAR();  /* arrival buf c^1 */                                           \
    }                                                                          \
  } while (0)

  // prologue: A[0](4),B[0](2) -> buf0 ; B[1](2) -> buf1 ; vmcnt(2) retires
  // {A[0], B[0]}, keeps B[1] in flight.
  STAGE_A(0, 0);
  STAGE_B(0, 0);
  STAGE_B(1, 1);
  asm volatile("s_waitcnt vmcnt(2)" ::: "memory");
  SCHED();
  __builtin_amdgcn_s_barrier();
  SCHED();

  #pragma unroll 1
  for (int it = 0; it < 7; ++it) {
    KT_BODY(2 * it, 0, 1, 1, 2, 0);
    KT_BODY(2 * it + 1, 1, 1, 1, 2, 0);
  }
  KT_BODY(14, 0, 1, 0, 0, 0);   // stages A[15]; no B[16]; vmcnt(0) drains all
  KT_BODY(15, 1, 0, 0, -1, 1);  // pure compute
#undef KT_BODY
#undef MFMA4
#undef READ_A1
#undef READ_B4
#undef STAGE_A
#undef STAGE_B

  // epilogue: d2 = x2[m] + p2[p] - 2*dot ; per-wave 64-col window, <=2 batches
  const int wm_base = m0 + wn * 64;
  const int b_lo = wm_base / 196;
  int b_hi = (wm_base + 63) / 196;
  if (b_hi > 31) b_hi = 31;
  const bool wave_ok = (b_lo < 32);
  float x2v[4];
  int seg0[4];
  #pragma unroll
  for (int ni = 0; ni < 4; ++ni) {
    const int m = wm_base + ni * 16 + lr;  // D col = lane&15
    x2v[ni] = x2[m];
    seg0[ni] = ((m / 196) == b_lo);
  }
  const float INF = __uint_as_float(INF_BITS);
  #pragma unroll
  for (int mi = 0; mi < 4; ++mi) {
    const int prow = p0 + wp * 64 + mi * 16 + 4 * lg;  // D row = 4*(lane>>4)+j
    #pragma unroll
    for (int j = 0; j < 4; ++j) {
      const int p = prow + j;
      const float pp = p2[p];
      float ma = INF, mb = INF;
      #pragma unroll
      for (int ni = 0; ni < 4; ++ni) {
        const float d2 = x2v[ni] + pp - 2.f * acc[mi][ni][j];
        ma = fminf(ma, seg0[ni] ? d2 : INF);
        mb = fminf(mb, seg0[ni] ? INF : d2);
      }
      #pragma unroll
      for (int off = 1; off < 16; off <<= 1) {
        ma = fminf(ma, __shfl_xor(ma, off));
        mb = fminf(mb, __shfl_xor(mb, off));
      }
      if (lr == 0 && p < 2000 && wave_ok) {
        atomicMin(&outu[6400 + b_lo * 2000 + p], __float_as_uint(fmaxf(ma, 0.f)));
        if (b_hi != b_lo)
          atomicMin(&outu[6400 + b_hi * 2000 + p], __float_as_uint(fmaxf(mb, 0.f)));
      }
    }
  }
}

// ---- post: d = sqrt(max(d2,1e-12)) in place; sim -> simbuf ----
__global__ void k_post(float* __restrict__ out, float* __restrict__ simbuf) {
  int i = blockIdx.x * blockDim.x + threadIdx.x;
  if (i >= 64000) return;
  float d2 = out[6400 + i];
  float d = sqrtf(fmaxf(d2, 1e-12f));
  out[6400 + i] = d;
  simbuf[i] = logf((d + 1.0f) / (d + 1e-7f));
}

// ---- scores: one wave per (b, class) pair ----
__global__ __launch_bounds__(256) void k_scores(const float* __restrict__ fc_w,
                                                const float* __restrict__ simbuf,
                                                float* __restrict__ out) {
  const int id = blockIdx.x * 4 + (threadIdx.x >> 6);  // 0..6399
  const int lane = threadIdx.x & 63;
  const int b = id / 200;
  const int c = id - b * 200;
  const f32x4* sv = (const f32x4*)(simbuf + (size_t)b * 2000);
  const f32x4* wv = (const f32x4*)(fc_w + (size_t)c * 2000);
  float s = 0.f;
  #pragma unroll
  for (int it = 0; it < 8; ++it) {
    int i = lane + it * 64;
    if (i < 500) {
      f32x4 a = sv[i], w4 = wv[i];
      s += a.x * w4.x + a.y * w4.y + a.z * w4.z + a.w * w4.w;
    }
  }
  #pragma unroll
  for (int off = 32; off; off >>= 1) s += __shfl_xor(s, off);
  if (lane == 0) out[b * 200 + c] = s;
}

extern "C" void kernel_launch(void* const* d_in, const int* in_sizes, int n_in,
                              void* d_out, int out_size, void* d_ws, size_t ws_size,
                              hipStream_t stream) {
  const float* x      = (const float*)d_in[0];  // (32, 2048, 14, 14) f32
  const float* protos = (const float*)d_in[1];  // (1, 2000, 2048) f32
  const float* fc_w   = (const float*)d_in[2];  // (200, 2000) f32
  float* out = (float*)d_out;                   // 6400 scores + 64000 min-dists

  char* wsb = (char*)d_ws;
  unsigned char* pTf = (unsigned char*)wsb;               // 2048*2048 = 4194304
  unsigned char* xTf = (unsigned char*)(wsb + 4194304);   // 6400*2048 = 13107200
  float* p2   = (float*)(wsb + 17301504);                 // 2048 f32
  float* x2   = (float*)(wsb + 17309696);                 // 6400 f32 (pad +inf)
  float* x2p  = (float*)(wsb + 17335296);                 // 32*6272 f32
  float* simb = (float*)(wsb + 17335296);                 // aliases x2p (dead after k_x2r)

  k_prep_p<<<2048, 256, 0, stream>>>(protos, pTf, p2, (unsigned int*)d_out);
  k_prep_x<<<dim3(32, 33), 256, 0, stream>>>(x, xTf, x2p, x2);
  k_x2r<<<25, 256, 0, stream>>>(x2p, x2);
  k_main<<<400, 512, 0, stream>>>(pTf, xTf, p2, x2, (unsigned int*)d_out);
  k_post<<<250, 256, 0, stream>>>(out, simb);
  k_scores<<<1600, 256, 0, stream>>>(fc_w, simb, out);
}